// Round 15
// baseline (97.036 us; speedup 1.0000x reference)
//
#include <hip/hip_runtime.h>
#include <hip/hip_bf16.h>
#include <cstdint>
#include <cstddef>

// Problem dims (fixed): B=4, S=2048, D=512, H=8, HD=64, M = B*S = 8192
#define S_LEN 2048
#define D_DIM 512
#define NHEAD 8
#define HDIM  64

typedef __attribute__((ext_vector_type(8)))  __bf16 b8;    // MFMA A/B fragment (4 VGPRs)
typedef __attribute__((ext_vector_type(4)))  __bf16 b4;    // 8-byte vector
typedef __attribute__((ext_vector_type(4)))  float  f4;    // 16x16 C fragment
typedef __attribute__((ext_vector_type(16))) float  f16v;  // 32x32 C fragment
typedef __attribute__((ext_vector_type(4)))  unsigned int u32x4;

#define AS_GLOBAL __attribute__((address_space(1)))
#define AS_LDS    __attribute__((address_space(3)))

__device__ __forceinline__ void load_lds16(const void* g, void* l) {
  __builtin_amdgcn_global_load_lds((const AS_GLOBAL void*)g, (AS_LDS void*)l, 16, 0, 0);
}

__device__ __forceinline__ f4 mfma16(b8 a, b8 b, f4 c) {
  return __builtin_amdgcn_mfma_f32_16x16x32_bf16(a, b, c, 0, 0, 0);
}
__device__ __forceinline__ f16v mfma32(b8 a, b8 b, f16v c) {
  return __builtin_amdgcn_mfma_f32_32x32x16_bf16(a, b, c, 0, 0, 0);
}

// single-instruction 2^x
__device__ __forceinline__ float exp2v(float x) {
#if __has_builtin(__builtin_amdgcn_exp2f)
  return __builtin_amdgcn_exp2f(x);
#else
  float r; asm("v_exp_f32 %0, %1" : "=v"(r) : "v"(x)); return r;
#endif
}

// v_cvt_pk_bf16_f32: D.lo = bf16(S0), D.hi = bf16(S1)
__device__ __forceinline__ unsigned int pkbf(float lo, float hi_) {
  unsigned int r;
  asm("v_cvt_pk_bf16_f32 %0, %1, %2" : "=v"(r) : "v"(lo), "v"(hi_));
  return r;
}

// cross-half (lane i <-> lane i^32) combine. NOTE (R7/R8 post-mortem): a
// self-exchange via v_permlane32_swap inside one asm block reads stale
// registers; permlane is only safe in the MKFRAG pattern (distinct-value
// operands, compiler-scheduled producers). Use the proven shfl_xor forms.
__device__ __forceinline__ float xhalf_max(float v) {
  return fmaxf(v, __shfl_xor(v, 32));
}
__device__ __forceinline__ float xhalf_add(float v) {
  return v + __shfl_xor(v, 32);
}

// Swizzled read from an LDS tile with 128-byte rows. Physical byte =
// row*128 + (bytecol ^ ((row&7)<<4)); staging pre-applies the same XOR to the
// global source column so logical data lands in the right slot (involution).
__device__ __forceinline__ b8 lds_frag(const __bf16* base, int row, int bc) {
  return *reinterpret_cast<const b8*>((const char*)base + row * 128 + (bc ^ ((row & 7) << 4)));
}

// ===================== fp32 -> bf16 conversion (x + all 4 weights, 1 launch) ===
// blocks [0,4096): x (8192x512). blocks [4096,5120): weights, 256 blocks each.
__global__ __launch_bounds__(256) void cvt_all_kernel(
    const float* __restrict__ x,
    const float* __restrict__ w0, const float* __restrict__ w1,
    const float* __restrict__ w2, const float* __restrict__ w3,
    __bf16* __restrict__ xo,
    __bf16* o0, __bf16* o1, __bf16* o2, __bf16* o3) {
  int bid = blockIdx.x;
  const float* in; __bf16* out; int idx;
  if (bid < 4096) {
    in = x; out = xo; idx = bid * 256 + threadIdx.x;
  } else {
    int r = bid - 4096;            // 0..1023
    int wsel = r >> 8;             // 0..3
    in  = wsel == 0 ? w0 : wsel == 1 ? w1 : wsel == 2 ? w2 : w3;
    out = wsel == 0 ? o0 : wsel == 1 ? o1 : wsel == 2 ? o2 : o3;
    idx = (r & 255) * 256 + threadIdx.x;
  }
  int i = idx * 4;
  float4 v = *reinterpret_cast<const float4*>(in + i);
  b4 o;
  o.x = (__bf16)v.x; o.y = (__bf16)v.y; o.z = (__bf16)v.z; o.w = (__bf16)v.w;
  *reinterpret_cast<b4*>(out + i) = o;
}

// ===================== GEMM core: C(64x128) = A * W^T =====================
// BM=64, BN=128 tile: A-stage 8KB, B-stage 16KB. 256 threads = 4 waves (2x2);
// per-wave output 32x64 -> acc[2][4]. launch_bounds(256,6) caps regs at 85 so
// the LDS-permitted 6 blocks/CU is actually reachable.
__device__ __forceinline__ void gemm_core(const __bf16* __restrict__ A, const __bf16* __restrict__ W,
                                          int m0, int n0, __bf16* As, __bf16* Bs, f4 acc[2][4]) {
  const int t = threadIdx.x;
  const int lane = t & 63;
  const int w = t >> 6, wr = w >> 1, wc = w & 1;
  const f4 zero = {0.f, 0.f, 0.f, 0.f};
  #pragma unroll
  for (int mi = 0; mi < 2; ++mi)
    #pragma unroll
    for (int ni = 0; ni < 4; ++ni) acc[mi][ni] = zero;

  const char* Ab = (const char*)A;
  const char* Wb = (const char*)W;
  for (int kt = 0; kt < 512; kt += 64) {
    __syncthreads();
    #pragma unroll
    for (int i = 0; i < 2; ++i) {        // A tile: 64x64 bf16 = 8 KB
      int o = i * 4096 + t * 16;
      int row = o >> 7, cb = o & 127;
      int scb = cb ^ ((row & 7) << 4);
      load_lds16(Ab + ((size_t)(m0 + row) * 512 + kt) * 2 + scb, (char*)As + o);
    }
    #pragma unroll
    for (int i = 0; i < 4; ++i) {        // B tile: 128x64 bf16 = 16 KB
      int o = i * 4096 + t * 16;
      int row = o >> 7, cb = o & 127;
      int scb = cb ^ ((row & 7) << 4);
      load_lds16(Wb + ((size_t)(n0 + row) * 512 + kt) * 2 + scb, (char*)Bs + o);
    }
    __syncthreads();
    #pragma unroll
    for (int kk = 0; kk < 2; ++kk) {
      b8 af[2], bf[4];
      #pragma unroll
      for (int mi = 0; mi < 2; ++mi)
        af[mi] = lds_frag(As, wr * 32 + mi * 16 + (lane & 15), kk * 64 + ((lane >> 4) << 4));
      #pragma unroll
      for (int ni = 0; ni < 4; ++ni)
        bf[ni] = lds_frag(Bs, wc * 64 + ni * 16 + (lane & 15), kk * 64 + ((lane >> 4) << 4));
      #pragma unroll
      for (int mi = 0; mi < 2; ++mi)
        #pragma unroll
        for (int ni = 0; ni < 4; ++ni)
          acc[mi][ni] = mfma16(af[mi], bf[ni], acc[mi][ni]);
    }
  }
}

// ===================== QKV projection =====================
// grid (128, 4, 3); z picks {Wq,Wk,Wv}. Q,K written [B,H,S,HD]; V written
// TRANSPOSED [B,H,HD,S] directly in the epilogue.
// Q pre-scaled by (1/sqrt(dk))*log2(e) so attention exp runs in base-2 domain.
__global__ __launch_bounds__(256, 6) void gemm_qkv_kernel(
    const __bf16* __restrict__ xb,
    const __bf16* __restrict__ wq, const __bf16* __restrict__ wk, const __bf16* __restrict__ wv,
    const float* __restrict__ bq, const float* __restrict__ bk, const float* __restrict__ bv,
    __bf16* Qo, __bf16* Ko, __bf16* Vto) {
  __shared__ __bf16 As[64 * 64];
  __shared__ __bf16 Bs[128 * 64];
  int z = blockIdx.z;
  const __bf16* W = z == 0 ? wq : (z == 1 ? wk : wv);
  const float* bias = z == 0 ? bq : (z == 1 ? bk : bv);
  const float sc = (z == 0) ? 0.18033688011112042f : 1.0f;  // 0.125 * log2(e)
  int m0 = blockIdx.x * 64, n0 = blockIdx.y * 128;
  f4 acc[2][4];
  gemm_core(xb, W, m0, n0, As, Bs, acc);
  int t = threadIdx.x, lane = t & 63, w = t >> 6, wr = w >> 1, wc = w & 1;
  if (z == 2) {
    // V^T epilogue: [B,H,HD,S]; r=0..3 -> s0..s0+3 at fixed hd -> b4 store.
    #pragma unroll
    for (int mi = 0; mi < 2; ++mi)
      #pragma unroll
      for (int ni = 0; ni < 4; ++ni) {
        int m = m0 + wr * 32 + mi * 16 + ((lane >> 4) << 2);   // r=0 row
        int n = n0 + wc * 64 + ni * 16 + (lane & 15);
        float bv_ = bias[n];
        b4 v;
        #pragma unroll
        for (int r = 0; r < 4; ++r) v[r] = (__bf16)(acc[mi][ni][r] + bv_);
        int b = m >> 11, s = m & 2047, h = n >> 6, hd = n & 63;
        *reinterpret_cast<b4*>(&Vto[(((size_t)(b * NHEAD + h)) * HDIM + hd) * S_LEN + s]) = v;
      }
  } else {
    __bf16* out = z == 0 ? Qo : Ko;
    #pragma unroll
    for (int mi = 0; mi < 2; ++mi)
      #pragma unroll
      for (int ni = 0; ni < 4; ++ni)
        #pragma unroll
        for (int r = 0; r < 4; ++r) {
          int m = m0 + wr * 32 + mi * 16 + ((lane >> 4) << 2) + r;
          int n = n0 + wc * 64 + ni * 16 + (lane & 15);
          float v = (acc[mi][ni][r] + bias[n]) * sc;
          int b = m >> 11, s = m & 2047, h = n >> 6, hd = n & 63;
          out[(((size_t)(b * NHEAD + h)) * S_LEN + s) * HDIM + hd] = (__bf16)v;
        }
  }
}

// ===================== output projection (64x64 tile, 4 blocks/CU) ============
// R13 post-mortem: gemm_o at 64x128 ran 512 blocks = 2 blocks/CU — the worst
// latency hiding in the pipeline. 64x64 -> grid (128,8) = 1024 blocks = 4/CU;
// LDS 16KB; extra A/B restage traffic is L2-resident (ctx 8.4MB + Wo 0.5MB).
__global__ __launch_bounds__(256, 6) void gemm_o_kernel(const __bf16* __restrict__ ctx,
                                                        const __bf16* __restrict__ wo,
                                                        const float* __restrict__ bo,
                                                        float* __restrict__ out) {
  __shared__ __bf16 As[64 * 64];
  __shared__ __bf16 Bs[64 * 64];
  const int t = threadIdx.x;
  const int lane = t & 63;
  const int w = t >> 6, wr = w >> 1, wc = w & 1;
  int m0 = blockIdx.x * 64, n0 = blockIdx.y * 64;
  const f4 zero = {0.f, 0.f, 0.f, 0.f};
  f4 acc[2][2];
  #pragma unroll
  for (int mi = 0; mi < 2; ++mi)
    #pragma unroll
    for (int ni = 0; ni < 2; ++ni) acc[mi][ni] = zero;

  const char* Ab = (const char*)ctx;
  const char* Wb = (const char*)wo;
  for (int kt = 0; kt < 512; kt += 64) {
    __syncthreads();
    #pragma unroll
    for (int i = 0; i < 2; ++i) {
      int o = i * 4096 + t * 16;
      int row = o >> 7, cb = o & 127;
      int scb = cb ^ ((row & 7) << 4);
      load_lds16(Ab + ((size_t)(m0 + row) * 512 + kt) * 2 + scb, (char*)As + o);
      load_lds16(Wb + ((size_t)(n0 + row) * 512 + kt) * 2 + scb, (char*)Bs + o);
    }
    __syncthreads();
    #pragma unroll
    for (int kk = 0; kk < 2; ++kk) {
      b8 af[2], bf[2];
      #pragma unroll
      for (int mi = 0; mi < 2; ++mi)
        af[mi] = lds_frag(As, wr * 32 + mi * 16 + (lane & 15), kk * 64 + ((lane >> 4) << 4));
      #pragma unroll
      for (int ni = 0; ni < 2; ++ni)
        bf[ni] = lds_frag(Bs, wc * 32 + ni * 16 + (lane & 15), kk * 64 + ((lane >> 4) << 4));
      #pragma unroll
      for (int mi = 0; mi < 2; ++mi)
        #pragma unroll
        for (int ni = 0; ni < 2; ++ni)
          acc[mi][ni] = mfma16(af[mi], bf[ni], acc[mi][ni]);
    }
  }

  #pragma unroll
  for (int mi = 0; mi < 2; ++mi)
    #pragma unroll
    for (int ni = 0; ni < 2; ++ni)
      #pragma unroll
      for (int r = 0; r < 4; ++r) {
        int m = m0 + wr * 32 + mi * 16 + ((lane >> 4) << 2) + r;
        int n = n0 + wc * 32 + ni * 16 + (lane & 15);
        out[(size_t)m * D_DIM + n] = acc[mi][ni][r] + bo[n];
      }
}

// ===================== flash attention (kv-split-2, 8 waves) =====================
// R9 structure + conditional cross-half exchange. NOTE: the constant
// SQ_LDS_BANK_CONFLICT=4194304 is intrinsic ds_read_b128 overhead
// (1048576 reads x 4 cy; m134: b128 ~12cy vs 8 ideal), NOT a fixable conflict.
#define NTG 16  // kv tiles per group: 1024 / 64

// Build PV B-fragment for one 16-k slot from C-layout f32 P regs base..base+7.
// v_permlane32_swap_b32: vdst.lanes[32:63] <-> vsrc.lanes[0:31]. swap(A0,B0):
//   lo lane: A0 = A0_own,     B0 = A0 from hi partner
//   hi lane: A0 = B0 from lo, B0 = B0_own
// -> fragment words [A0, A1, B0, B1] for both halves. (Producers are separate
// asm blocks; compiler scheduling provides the permlane hazard distance.)
#define MKFRAG(dst, st, base) do {                                   \
    unsigned int A0_ = pkbf((st)[(base)+0], (st)[(base)+1]);         \
    unsigned int A1_ = pkbf((st)[(base)+2], (st)[(base)+3]);         \
    unsigned int B0_ = pkbf((st)[(base)+4], (st)[(base)+5]);         \
    unsigned int B1_ = pkbf((st)[(base)+6], (st)[(base)+7]);         \
    asm("v_permlane32_swap_b32 %0, %1" : "+v"(A0_), "+v"(B0_));      \
    asm("v_permlane32_swap_b32 %0, %1" : "+v"(A1_), "+v"(B1_));      \
    u32x4 wv_; wv_.x = A0_; wv_.y = A1_; wv_.z = B0_; wv_.w = B1_;   \
    dst = __builtin_bit_cast(b8, wv_);                               \
  } while (0)

// One 64-kv tile. KO/VO are compile-time byte offsets of the K / V tiles.
#define TILE(KO, VO) do {                                                     \
    f16v t0 = Z16, t1 = Z16;                                                  \
    __builtin_amdgcn_s_setprio(1);                                            \
    _Pragma("unroll")                                                         \
    for (int ks = 0; ks < 4; ++ks) {                                          \
      b8 kf0 = *reinterpret_cast<const AS_LDS b8*>(sb + koff[ks] + (KO));     \
      b8 kf1 = *reinterpret_cast<const AS_LDS b8*>(sb + koff[ks] + (KO) + 4096); \
      t0 = mfma32(kf0, qf[ks], t0);                                           \
      t1 = mfma32(kf1, qf[ks], t1);                                           \
    }                                                                         \
    __builtin_amdgcn_s_setprio(0);                                            \
    float a0 = fmaxf(fmaxf(t0[0], t0[8]),  fmaxf(t1[0], t1[8]));              \
    float a1 = fmaxf(fmaxf(t0[1], t0[9]),  fmaxf(t1[1], t1[9]));              \
    float a2 = fmaxf(fmaxf(t0[2], t0[10]), fmaxf(t1[2], t1[10]));             \
    float a3 = fmaxf(fmaxf(t0[3], t0[11]), fmaxf(t1[3], t1[11]));             \
    float a4 = fmaxf(fmaxf(t0[4], t0[12]), fmaxf(t1[4], t1[12]));             \
    float a5 = fmaxf(fmaxf(t0[5], t0[13]), fmaxf(t1[5], t1[13]));             \
    float a6 = fmaxf(fmaxf(t0[6], t0[14]), fmaxf(t1[6], t1[14]));             \
    float a7 = fmaxf(fmaxf(t0[7], t0[15]), fmaxf(t1[7], t1[15]));             \
    float mx = fmaxf(fmaxf(fmaxf(a0, a1), fmaxf(a2, a3)),                     \
                     fmaxf(fmaxf(a4, a5), fmaxf(a6, a7)));                    \
    if (!__all(mx - mr <= 11.5f)) {                                           \
      mx = xhalf_max(mx);              /* true global max (rare path) */      \
      float mn = fmaxf(mr, mx);                                               \
      float al = exp2v(mr - mn);                                              \
      mr = mn; lsum *= al; o0 *= al; o1 *= al;                                \
    }                                                                         \
    _Pragma("unroll")                                                         \
    for (int r = 0; r < 16; ++r) t0[r] = exp2v(t0[r] - mr);                   \
    _Pragma("unroll")                                                         \
    for (int r = 0; r < 16; ++r) t1[r] = exp2v(t1[r] - mr);                   \
    {                                                                         \
      float p0 = (t0[0] + t1[0]) + (t0[8]  + t1[8]);                          \
      float p1 = (t0[1] + t1[1]) + (t0[9]  + t1[9]);                          \
      float p2 = (t0[2] + t1[2]) + (t0[10] + t1[10]);                         \
      float p3 = (t0[3] + t1[3]) + (t0[11] + t1[11]);                         \
      float p4 = (t0[4] + t1[4]) + (t0[12] + t1[12]);                         \
      float p5 = (t0[5] + t1[5]) + (t0[13] + t1[13]);                         \
      float p6 = (t0[6] + t1[6]) + (t0[14] + t1[14]);                         \
      float p7 = (t0[7] + t1[7]) + (t0[15] + t1[15]);                         \
      lsum += ((p0 + p1) + (p2 + p3)) + ((p4 + p5) + (p6 + p7));              \
    }                                                                         \
    __builtin_amdgcn_s_setprio(1);                                            \
    _Pragma("unroll")                                                         \
    for (int ks = 0; ks < 4; ++ks) {                                          \
      b8 pa;                                                                  \
      if (ks == 0)      MKFRAG(pa, t0, 0);                                    \
      else if (ks == 1) MKFRAG(pa, t0, 8);                                    \
      else if (ks == 2) MKFRAG(pa, t1, 0);                                    \
      else              MKFRAG(pa, t1, 8);                                    \
      b8 vf0 = *reinterpret_cast<const AS_LDS b8*>(sb + koff[ks] + (VO));     \
      b8 vf1 = *reinterpret_cast<const AS_LDS b8*>(sb + koff[ks] + (VO) + 4096); \
      o0 = mfma32(vf0, pa, o0);                                               \
      o1 = mfma32(vf1, pa, o1);                                               \
    }                                                                         \
    __builtin_amdgcn_s_setprio(0);                                            \
  } while (0)

__global__ __launch_bounds__(512, 4) void attn_kernel(const __bf16* __restrict__ Q,
                                                      const __bf16* __restrict__ K,
                                                      const __bf16* __restrict__ Vt,
                                                      __bf16* __restrict__ ctx) {
  __shared__ char smem_[65536];
  int t = threadIdx.x, lane = t & 63, w = t >> 6;
  int lane31 = lane & 31, hi = lane >> 5;
  int grp = w >> 2, qs = w & 3, t256 = t & 255;

  // XCD swizzle: 512 blocks, 8 XCDs -> 64-block contiguous chunk per XCD
  // = 4 whole heads per XCD (16 q-tiles x same bh -> K/V L2-resident).
  int bid = blockIdx.x;
  int nid = (bid & 7) * 64 + (bid >> 3);
  int bh = nid >> 4, qtile = nid & 15;
  int b = bh >> 3, h = bh & 7;
  int q = qtile * 128 + qs * 32 + lane31;   // this lane's q row
  const __bf16* Qp = Q + (size_t)bh * S_LEN * HDIM;
  const __bf16* Kp = K + (size_t)bh * S_LEN * HDIM;
  const __bf16* Vp = Vt + (size_t)bh * HDIM * S_LEN;
  const int kv0 = grp * (S_LEN / 2);

  // Q fragments (B-operand: col=q=lane31, k=d=ks*16+hi*8+e). Q pre-scaled.
  b8 qf[4];
  #pragma unroll
  for (int ks = 0; ks < 4; ++ks)
    qf[ks] = *reinterpret_cast<const b8*>(&Qp[(size_t)q * HDIM + ks * 16 + hi * 8]);

  // 32-bit LDS base + per-ks fragment offsets (half1 = +4096 immediate since
  // (row+32)&7 == row&7). koff folds in grp*16384.
  const AS_LDS char* sb = (const AS_LDS char*)smem_;
  unsigned koff[4];
  #pragma unroll
  for (int ks = 0; ks < 4; ++ks) {
    int bc = hi * 16 + ks * 32;
    koff[ks] = grp * 16384 + lane31 * 128 + (bc ^ ((lane31 & 7) << 4));
  }

  // staging addresses (strength-reduced per iteration)
  int oA = t256 * 16, oB = 4096 + t256 * 16;
  int rA = oA >> 7, rB = oB >> 7;
  int sA = (oA & 127) ^ ((rA & 7) << 4), sB = (oB & 127) ^ ((rB & 7) << 4);
  const char* KgA = (const char*)Kp + (size_t)(kv0 + rA) * 128 + sA;   // += 8192/iter
  const char* KgB = (const char*)Kp + (size_t)(kv0 + rB) * 128 + sB;
  const char* VgA = (const char*)Vp + (size_t)rA * (S_LEN * 2) + (size_t)kv0 * 2 + sA;  // += 128/iter
  const char* VgB = (const char*)Vp + (size_t)rB * (S_LEN * 2) + (size_t)kv0 * 2 + sB;

  const f16v Z16 = {0,0,0,0,0,0,0,0,0,0,0,0,0,0,0,0};
  f16v o0 = Z16, o1 = Z16;   // O^T accum: rows d (0-31 / 32-63), col q
  float mr = -1e30f, lsum = 0.f;

  auto stage = [&](int buf) {
    char* ldsK = smem_ + grp * 16384 + buf * 8192;
    load_lds16(KgA, ldsK + oA);
    load_lds16(KgB, ldsK + oB);
    load_lds16(VgA, ldsK + 32768 + oA);
    load_lds16(VgB, ldsK + 32768 + oB);
    KgA += 8192; KgB += 8192; VgA += 128; VgB += 128;
  };

  stage(0);
  __syncthreads();

  #pragma unroll 1
  for (int it2 = 0; it2 < NTG / 2; ++it2) {
    stage(1);
    TILE(0, 32768);
    __syncthreads();
    if (it2 < NTG / 2 - 1) stage(0);
    TILE(8192, 40960);
    __syncthreads();
  }

  // ---- merge the two kv-halves (grp1 -> LDS -> grp0), then write ctx ----
  float l_own = xhalf_add(lsum);      // both halves' kv columns combined
  float* OL = (float*)smem_;          // [4 qs][64 d][32 q] f32 = 32 KiB (staging dead)
  float* ML = OL + 8192;              // m[4][32] then l[4][32]
  if (grp == 1) {
    #pragma unroll
    for (int g = 0; g < 4; ++g)
      #pragma unroll
      for (int j = 0; j < 4; ++j) {
        int d = 8 * g + 4 * hi + j;
        OL[(qs * 64 + d) * 32 + lane31]      = o0[4 * g + j];
        OL[(qs * 64 + 32 + d) * 32 + lane31] = o1[4 * g + j];
      }
    if (hi == 0) { ML[qs * 32 + lane31] = mr; ML[128 + qs * 32 + lane31] = l_own; }
  }
  __syncthreads();
  if (grp == 0) {
    float m1 = ML[qs * 32 + lane31], l1 = ML[128 + qs * 32 + lane31];
    float mm = fmaxf(mr, m1);
    float s0 = exp2v(mr - mm), s1 = exp2v(m1 - mm);
    float inv = 1.0f / (l_own * s0 + l1 * s1);
    __bf16* cp = ctx + (size_t)b * S_LEN * D_DIM + (size_t)q * D_DIM + (size_t)h * HDIM;
    #pragma unroll
    for (int g = 0; g < 4; ++g) {
      b4 v0, v1;
      #pragma unroll
      for (int j = 0; j < 4; ++j) {
        int d = 8 * g + 4 * hi + j;
        v0[j] = (__bf16)((o0[4 * g + j] * s0 + OL[(qs * 64 + d) * 32 + lane31] * s1) * inv);
        v1[j] = (__bf16)((o1[4 * g + j] * s0 + OL[(qs * 64 + 32 + d) * 32 + lane31] * s1) * inv);
      }
      int d0 = 8 * g + 4 * hi;
      *reinterpret_cast<b4*>(cp + d0)      = v0;
      *reinterpret_cast<b4*>(cp + 32 + d0) = v1;
    }
  }
}

// ===================== launch =====================
extern "C" void kernel_launch(void* const* d_in, const int* in_sizes, int n_in,
                              void* d_out, int out_size, void* d_ws, size_t ws_size,
                              hipStream_t stream) {
  const float* x  = (const float*)d_in[0];
  const float* Wq = (const float*)d_in[1];
  const float* bq = (const float*)d_in[2];
  const float* Wk = (const float*)d_in[3];
  const float* bk = (const float*)d_in[4];
  const float* Wv = (const float*)d_in[5];
  const float* bv = (const float*)d_in[6];
  const float* Wo = (const float*)d_in[7];
  const float* bo = (const float*)d_in[8];
  float* out = (float*)d_out;

  char* ws = (char*)d_ws;
  __bf16* xb   = (__bf16*)(ws);                               // 8192*512
  __bf16* wqb  = xb  + 4194304;                               // 512*512
  __bf16* wkb  = wqb + 262144;
  __bf16* wvb  = wkb + 262144;
  __bf16* wob  = wvb + 262144;
  __bf16* Qb   = wob + 262144;                                // 4*8*2048*64
  __bf16* Kb   = Qb  + 4194304;
  __bf16* Vtb  = Kb  + 4194304;                               // V transposed [B,H,HD,S]
  __bf16* ctxb = xb;  // reuse (x dead after QKV)

  cvt_all_kernel<<<dim3(5120), dim3(256), 0, stream>>>(x, Wq, Wk, Wv, Wo, xb, wqb, wkb, wvb, wob);
  gemm_qkv_kernel<<<dim3(128, 4, 3), dim3(256), 0, stream>>>(xb, wqb, wkb, wvb, bq, bk, bv, Qb, Kb, Vtb);
  attn_kernel<<<dim3(512), dim3(512), 0, stream>>>(Qb, Kb, Vtb, ctxb);
  gemm_o_kernel<<<dim3(128, 8), dim3(256), 0, stream>>>(ctxb, wob, bo, out);
}

// Round 16
// 91.358 us; speedup vs baseline: 1.0622x; 1.0622x over previous
//
#include <hip/hip_runtime.h>
#include <hip/hip_bf16.h>
#include <cstdint>
#include <cstddef>

// Problem dims (fixed): B=4, S=2048, D=512, H=8, HD=64, M = B*S = 8192
#define S_LEN 2048
#define D_DIM 512
#define NHEAD 8
#define HDIM  64

typedef __attribute__((ext_vector_type(8)))  __bf16 b8;    // MFMA A/B fragment (4 VGPRs)
typedef __attribute__((ext_vector_type(4)))  __bf16 b4;    // 8-byte vector
typedef __attribute__((ext_vector_type(4)))  float  f4;    // 16x16 C fragment
typedef __attribute__((ext_vector_type(16))) float  f16v;  // 32x32 C fragment
typedef __attribute__((ext_vector_type(4)))  unsigned int u32x4;

#define AS_GLOBAL __attribute__((address_space(1)))
#define AS_LDS    __attribute__((address_space(3)))

__device__ __forceinline__ void load_lds16(const void* g, void* l) {
  __builtin_amdgcn_global_load_lds((const AS_GLOBAL void*)g, (AS_LDS void*)l, 16, 0, 0);
}

__device__ __forceinline__ f4 mfma16(b8 a, b8 b, f4 c) {
  return __builtin_amdgcn_mfma_f32_16x16x32_bf16(a, b, c, 0, 0, 0);
}
__device__ __forceinline__ f16v mfma32(b8 a, b8 b, f16v c) {
  return __builtin_amdgcn_mfma_f32_32x32x16_bf16(a, b, c, 0, 0, 0);
}

// single-instruction 2^x
__device__ __forceinline__ float exp2v(float x) {
#if __has_builtin(__builtin_amdgcn_exp2f)
  return __builtin_amdgcn_exp2f(x);
#else
  float r; asm("v_exp_f32 %0, %1" : "=v"(r) : "v"(x)); return r;
#endif
}

// v_cvt_pk_bf16_f32: D.lo = bf16(S0), D.hi = bf16(S1)
__device__ __forceinline__ unsigned int pkbf(float lo, float hi_) {
  unsigned int r;
  asm("v_cvt_pk_bf16_f32 %0, %1, %2" : "=v"(r) : "v"(lo), "v"(hi_));
  return r;
}

// cross-half (lane i <-> lane i^32) combine. NOTE (R7/R8 post-mortem): a
// self-exchange via v_permlane32_swap inside one asm block reads stale
// registers; permlane is only safe in the MKFRAG pattern (distinct-value
// operands, compiler-scheduled producers). Use the proven shfl_xor forms.
__device__ __forceinline__ float xhalf_max(float v) {
  return fmaxf(v, __shfl_xor(v, 32));
}
__device__ __forceinline__ float xhalf_add(float v) {
  return v + __shfl_xor(v, 32);
}

// Swizzled read from an LDS tile with 128-byte rows. Physical byte =
// row*128 + (bytecol ^ ((row&7)<<4)); staging pre-applies the same XOR to the
// global source column so logical data lands in the right slot (involution).
__device__ __forceinline__ b8 lds_frag(const __bf16* base, int row, int bc) {
  return *reinterpret_cast<const b8*>((const char*)base + row * 128 + (bc ^ ((row & 7) << 4)));
}

// ===================== fp32 -> bf16 conversion =====================
__global__ __launch_bounds__(256) void cvt_kernel(const float* __restrict__ in,
                                                  __bf16* __restrict__ out) {
  int i = (blockIdx.x * 256 + threadIdx.x) * 4;
  float4 v = *reinterpret_cast<const float4*>(in + i);
  b4 o;
  o.x = (__bf16)v.x; o.y = (__bf16)v.y; o.z = (__bf16)v.z; o.w = (__bf16)v.w;
  *reinterpret_cast<b4*>(out + i) = o;
}

__global__ __launch_bounds__(256) void cvt_w_kernel(const float* __restrict__ w0, const float* __restrict__ w1,
                                                    const float* __restrict__ w2, const float* __restrict__ w3,
                                                    __bf16* o0, __bf16* o1, __bf16* o2, __bf16* o3) {
  const float* in = blockIdx.y == 0 ? w0 : blockIdx.y == 1 ? w1 : blockIdx.y == 2 ? w2 : w3;
  __bf16* out     = blockIdx.y == 0 ? o0 : blockIdx.y == 1 ? o1 : blockIdx.y == 2 ? o2 : o3;
  int i = (blockIdx.x * 256 + threadIdx.x) * 4;
  float4 v = *reinterpret_cast<const float4*>(in + i);
  b4 o;
  o.x = (__bf16)v.x; o.y = (__bf16)v.y; o.z = (__bf16)v.z; o.w = (__bf16)v.w;
  *reinterpret_cast<b4*>(out + i) = o;
}

// ===================== GEMM core: C(64x128) = A * W^T =====================
// BM=64, BN=128 tile: 2-6 blocks/CU so the 2-barrier K-loop overlaps across
// blocks. A-stage 8KB, B-stage 16KB. 256 threads = 4 waves (2x2); per-wave
// output 32x64 -> acc[2][4]. (R14 lesson: no launch_bounds-min — caps VGPR
// below the core's ~95 and spills; 64x64 gemm_o tile halves arithmetic
// intensity and regresses despite higher occupancy.)
__device__ __forceinline__ void gemm_core(const __bf16* __restrict__ A, const __bf16* __restrict__ W,
                                          int m0, int n0, __bf16* As, __bf16* Bs, f4 acc[2][4]) {
  const int t = threadIdx.x;
  const int lane = t & 63;
  const int w = t >> 6, wr = w >> 1, wc = w & 1;
  const f4 zero = {0.f, 0.f, 0.f, 0.f};
  #pragma unroll
  for (int mi = 0; mi < 2; ++mi)
    #pragma unroll
    for (int ni = 0; ni < 4; ++ni) acc[mi][ni] = zero;

  const char* Ab = (const char*)A;
  const char* Wb = (const char*)W;
  for (int kt = 0; kt < 512; kt += 64) {
    __syncthreads();
    #pragma unroll
    for (int i = 0; i < 2; ++i) {        // A tile: 64x64 bf16 = 8 KB
      int o = i * 4096 + t * 16;
      int row = o >> 7, cb = o & 127;
      int scb = cb ^ ((row & 7) << 4);
      load_lds16(Ab + ((size_t)(m0 + row) * 512 + kt) * 2 + scb, (char*)As + o);
    }
    #pragma unroll
    for (int i = 0; i < 4; ++i) {        // B tile: 128x64 bf16 = 16 KB
      int o = i * 4096 + t * 16;
      int row = o >> 7, cb = o & 127;
      int scb = cb ^ ((row & 7) << 4);
      load_lds16(Wb + ((size_t)(n0 + row) * 512 + kt) * 2 + scb, (char*)Bs + o);
    }
    __syncthreads();
    #pragma unroll
    for (int kk = 0; kk < 2; ++kk) {
      b8 af[2], bf[4];
      #pragma unroll
      for (int mi = 0; mi < 2; ++mi)
        af[mi] = lds_frag(As, wr * 32 + mi * 16 + (lane & 15), kk * 64 + ((lane >> 4) << 4));
      #pragma unroll
      for (int ni = 0; ni < 4; ++ni)
        bf[ni] = lds_frag(Bs, wc * 64 + ni * 16 + (lane & 15), kk * 64 + ((lane >> 4) << 4));
      #pragma unroll
      for (int mi = 0; mi < 2; ++mi)
        #pragma unroll
        for (int ni = 0; ni < 4; ++ni)
          acc[mi][ni] = mfma16(af[mi], bf[ni], acc[mi][ni]);
    }
  }
}

// ===================== QKV projection =====================
// grid (128, 4, 3); z picks {Wq,Wk,Wv}. Q,K written [B,H,S,HD]; V written
// TRANSPOSED [B,H,HD,S] directly in the epilogue.
// Q pre-scaled by (1/sqrt(dk))*log2(e) so attention exp runs in base-2 domain.
__global__ __launch_bounds__(256) void gemm_qkv_kernel(
    const __bf16* __restrict__ xb,
    const __bf16* __restrict__ wq, const __bf16* __restrict__ wk, const __bf16* __restrict__ wv,
    const float* __restrict__ bq, const float* __restrict__ bk, const float* __restrict__ bv,
    __bf16* Qo, __bf16* Ko, __bf16* Vto) {
  __shared__ __bf16 As[64 * 64];
  __shared__ __bf16 Bs[128 * 64];
  int z = blockIdx.z;
  const __bf16* W = z == 0 ? wq : (z == 1 ? wk : wv);
  const float* bias = z == 0 ? bq : (z == 1 ? bk : bv);
  const float sc = (z == 0) ? 0.18033688011112042f : 1.0f;  // 0.125 * log2(e)
  int m0 = blockIdx.x * 64, n0 = blockIdx.y * 128;
  f4 acc[2][4];
  gemm_core(xb, W, m0, n0, As, Bs, acc);
  int t = threadIdx.x, lane = t & 63, w = t >> 6, wr = w >> 1, wc = w & 1;
  if (z == 2) {
    // V^T epilogue: [B,H,HD,S]; r=0..3 -> s0..s0+3 at fixed hd -> b4 store.
    #pragma unroll
    for (int mi = 0; mi < 2; ++mi)
      #pragma unroll
      for (int ni = 0; ni < 4; ++ni) {
        int m = m0 + wr * 32 + mi * 16 + ((lane >> 4) << 2);   // r=0 row
        int n = n0 + wc * 64 + ni * 16 + (lane & 15);
        float bv_ = bias[n];
        b4 v;
        #pragma unroll
        for (int r = 0; r < 4; ++r) v[r] = (__bf16)(acc[mi][ni][r] + bv_);
        int b = m >> 11, s = m & 2047, h = n >> 6, hd = n & 63;
        *reinterpret_cast<b4*>(&Vto[(((size_t)(b * NHEAD + h)) * HDIM + hd) * S_LEN + s]) = v;
      }
  } else {
    __bf16* out = z == 0 ? Qo : Ko;
    #pragma unroll
    for (int mi = 0; mi < 2; ++mi)
      #pragma unroll
      for (int ni = 0; ni < 4; ++ni)
        #pragma unroll
        for (int r = 0; r < 4; ++r) {
          int m = m0 + wr * 32 + mi * 16 + ((lane >> 4) << 2) + r;
          int n = n0 + wc * 64 + ni * 16 + (lane & 15);
          float v = (acc[mi][ni][r] + bias[n]) * sc;
          int b = m >> 11, s = m & 2047, h = n >> 6, hd = n & 63;
          out[(((size_t)(b * NHEAD + h)) * S_LEN + s) * HDIM + hd] = (__bf16)v;
        }
  }
}

// ===================== output projection =====================
__global__ __launch_bounds__(256) void gemm_o_kernel(const __bf16* __restrict__ ctx,
                                                     const __bf16* __restrict__ wo,
                                                     const float* __restrict__ bo,
                                                     float* __restrict__ out) {
  __shared__ __bf16 As[64 * 64];
  __shared__ __bf16 Bs[128 * 64];
  int m0 = blockIdx.x * 64, n0 = blockIdx.y * 128;
  f4 acc[2][4];
  gemm_core(ctx, wo, m0, n0, As, Bs, acc);
  int t = threadIdx.x, lane = t & 63, w = t >> 6, wr = w >> 1, wc = w & 1;
  #pragma unroll
  for (int mi = 0; mi < 2; ++mi)
    #pragma unroll
    for (int ni = 0; ni < 4; ++ni)
      #pragma unroll
      for (int r = 0; r < 4; ++r) {
        int m = m0 + wr * 32 + mi * 16 + ((lane >> 4) << 2) + r;
        int n = n0 + wc * 64 + ni * 16 + (lane & 15);
        out[(size_t)m * D_DIM + n] = acc[mi][ni][r] + bo[n];
      }
}

// ===================== flash attention (kv-split-2, 8 waves) =====================
// R9 structure + conditional cross-half exchange. NOTE: the constant
// SQ_LDS_BANK_CONFLICT=4194304 is intrinsic ds_read_b128 overhead
// (1048576 reads x 4 cy; m134: b128 ~12cy vs 8 ideal), NOT a fixable conflict.
#define NTG 16  // kv tiles per group: 1024 / 64

// Build PV B-fragment for one 16-k slot from C-layout f32 P regs base..base+7.
// v_permlane32_swap_b32: vdst.lanes[32:63] <-> vsrc.lanes[0:31]. swap(A0,B0):
//   lo lane: A0 = A0_own,     B0 = A0 from hi partner
//   hi lane: A0 = B0 from lo, B0 = B0_own
// -> fragment words [A0, A1, B0, B1] for both halves. (Producers are separate
// asm blocks; compiler scheduling provides the permlane hazard distance.)
#define MKFRAG(dst, st, base) do {                                   \
    unsigned int A0_ = pkbf((st)[(base)+0], (st)[(base)+1]);         \
    unsigned int A1_ = pkbf((st)[(base)+2], (st)[(base)+3]);         \
    unsigned int B0_ = pkbf((st)[(base)+4], (st)[(base)+5]);         \
    unsigned int B1_ = pkbf((st)[(base)+6], (st)[(base)+7]);         \
    asm("v_permlane32_swap_b32 %0, %1" : "+v"(A0_), "+v"(B0_));      \
    asm("v_permlane32_swap_b32 %0, %1" : "+v"(A1_), "+v"(B1_));      \
    u32x4 wv_; wv_.x = A0_; wv_.y = A1_; wv_.z = B0_; wv_.w = B1_;   \
    dst = __builtin_bit_cast(b8, wv_);                               \
  } while (0)

// One 64-kv tile. KO/VO are compile-time byte offsets of the K / V tiles.
#define TILE(KO, VO) do {                                                     \
    f16v t0 = Z16, t1 = Z16;                                                  \
    __builtin_amdgcn_s_setprio(1);                                            \
    _Pragma("unroll")                                                         \
    for (int ks = 0; ks < 4; ++ks) {                                          \
      b8 kf0 = *reinterpret_cast<const AS_LDS b8*>(sb + koff[ks] + (KO));     \
      b8 kf1 = *reinterpret_cast<const AS_LDS b8*>(sb + koff[ks] + (KO) + 4096); \
      t0 = mfma32(kf0, qf[ks], t0);                                           \
      t1 = mfma32(kf1, qf[ks], t1);                                           \
    }                                                                         \
    __builtin_amdgcn_s_setprio(0);                                            \
    float a0 = fmaxf(fmaxf(t0[0], t0[8]),  fmaxf(t1[0], t1[8]));              \
    float a1 = fmaxf(fmaxf(t0[1], t0[9]),  fmaxf(t1[1], t1[9]));              \
    float a2 = fmaxf(fmaxf(t0[2], t0[10]), fmaxf(t1[2], t1[10]));             \
    float a3 = fmaxf(fmaxf(t0[3], t0[11]), fmaxf(t1[3], t1[11]));             \
    float a4 = fmaxf(fmaxf(t0[4], t0[12]), fmaxf(t1[4], t1[12]));             \
    float a5 = fmaxf(fmaxf(t0[5], t0[13]), fmaxf(t1[5], t1[13]));             \
    float a6 = fmaxf(fmaxf(t0[6], t0[14]), fmaxf(t1[6], t1[14]));             \
    float a7 = fmaxf(fmaxf(t0[7], t0[15]), fmaxf(t1[7], t1[15]));             \
    float mx = fmaxf(fmaxf(fmaxf(a0, a1), fmaxf(a2, a3)),                     \
                     fmaxf(fmaxf(a4, a5), fmaxf(a6, a7)));                    \
    if (!__all(mx - mr <= 11.5f)) {                                           \
      mx = xhalf_max(mx);              /* true global max (rare path) */      \
      float mn = fmaxf(mr, mx);                                               \
      float al = exp2v(mr - mn);                                              \
      mr = mn; lsum *= al; o0 *= al; o1 *= al;                                \
    }                                                                         \
    _Pragma("unroll")                                                         \
    for (int r = 0; r < 16; ++r) t0[r] = exp2v(t0[r] - mr);                   \
    _Pragma("unroll")                                                         \
    for (int r = 0; r < 16; ++r) t1[r] = exp2v(t1[r] - mr);                   \
    {                                                                         \
      float p0 = (t0[0] + t1[0]) + (t0[8]  + t1[8]);                          \
      float p1 = (t0[1] + t1[1]) + (t0[9]  + t1[9]);                          \
      float p2 = (t0[2] + t1[2]) + (t0[10] + t1[10]);                         \
      float p3 = (t0[3] + t1[3]) + (t0[11] + t1[11]);                         \
      float p4 = (t0[4] + t1[4]) + (t0[12] + t1[12]);                         \
      float p5 = (t0[5] + t1[5]) + (t0[13] + t1[13]);                         \
      float p6 = (t0[6] + t1[6]) + (t0[14] + t1[14]);                         \
      float p7 = (t0[7] + t1[7]) + (t0[15] + t1[15]);                         \
      lsum += ((p0 + p1) + (p2 + p3)) + ((p4 + p5) + (p6 + p7));              \
    }                                                                         \
    __builtin_amdgcn_s_setprio(1);                                            \
    _Pragma("unroll")                                                         \
    for (int ks = 0; ks < 4; ++ks) {                                          \
      b8 pa;                                                                  \
      if (ks == 0)      MKFRAG(pa, t0, 0);                                    \
      else if (ks == 1) MKFRAG(pa, t0, 8);                                    \
      else if (ks == 2) MKFRAG(pa, t1, 0);                                    \
      else              MKFRAG(pa, t1, 8);                                    \
      b8 vf0 = *reinterpret_cast<const AS_LDS b8*>(sb + koff[ks] + (VO));     \
      b8 vf1 = *reinterpret_cast<const AS_LDS b8*>(sb + koff[ks] + (VO) + 4096); \
      o0 = mfma32(vf0, pa, o0);                                               \
      o1 = mfma32(vf1, pa, o1);                                               \
    }                                                                         \
    __builtin_amdgcn_s_setprio(0);                                            \
  } while (0)

__global__ __launch_bounds__(512, 4) void attn_kernel(const __bf16* __restrict__ Q,
                                                      const __bf16* __restrict__ K,
                                                      const __bf16* __restrict__ Vt,
                                                      __bf16* __restrict__ ctx) {
  __shared__ char smem_[65536];
  int t = threadIdx.x, lane = t & 63, w = t >> 6;
  int lane31 = lane & 31, hi = lane >> 5;
  int grp = w >> 2, qs = w & 3, t256 = t & 255;

  // XCD swizzle: 512 blocks, 8 XCDs -> 64-block contiguous chunk per XCD
  // = 4 whole heads per XCD (16 q-tiles x same bh -> K/V L2-resident).
  int bid = blockIdx.x;
  int nid = (bid & 7) * 64 + (bid >> 3);
  int bh = nid >> 4, qtile = nid & 15;
  int b = bh >> 3, h = bh & 7;
  int q = qtile * 128 + qs * 32 + lane31;   // this lane's q row
  const __bf16* Qp = Q + (size_t)bh * S_LEN * HDIM;
  const __bf16* Kp = K + (size_t)bh * S_LEN * HDIM;
  const __bf16* Vp = Vt + (size_t)bh * HDIM * S_LEN;
  const int kv0 = grp * (S_LEN / 2);

  // Q fragments (B-operand: col=q=lane31, k=d=ks*16+hi*8+e). Q pre-scaled.
  b8 qf[4];
  #pragma unroll
  for (int ks = 0; ks < 4; ++ks)
    qf[ks] = *reinterpret_cast<const b8*>(&Qp[(size_t)q * HDIM + ks * 16 + hi * 8]);

  // 32-bit LDS base + per-ks fragment offsets (half1 = +4096 immediate since
  // (row+32)&7 == row&7). koff folds in grp*16384.
  const AS_LDS char* sb = (const AS_LDS char*)smem_;
  unsigned koff[4];
  #pragma unroll
  for (int ks = 0; ks < 4; ++ks) {
    int bc = hi * 16 + ks * 32;
    koff[ks] = grp * 16384 + lane31 * 128 + (bc ^ ((lane31 & 7) << 4));
  }

  // staging addresses (strength-reduced per iteration)
  int oA = t256 * 16, oB = 4096 + t256 * 16;
  int rA = oA >> 7, rB = oB >> 7;
  int sA = (oA & 127) ^ ((rA & 7) << 4), sB = (oB & 127) ^ ((rB & 7) << 4);
  const char* KgA = (const char*)Kp + (size_t)(kv0 + rA) * 128 + sA;   // += 8192/iter
  const char* KgB = (const char*)Kp + (size_t)(kv0 + rB) * 128 + sB;
  const char* VgA = (const char*)Vp + (size_t)rA * (S_LEN * 2) + (size_t)kv0 * 2 + sA;  // += 128/iter
  const char* VgB = (const char*)Vp + (size_t)rB * (S_LEN * 2) + (size_t)kv0 * 2 + sB;

  const f16v Z16 = {0,0,0,0,0,0,0,0,0,0,0,0,0,0,0,0};
  f16v o0 = Z16, o1 = Z16;   // O^T accum: rows d (0-31 / 32-63), col q
  float mr = -1e30f, lsum = 0.f;

  auto stage = [&](int buf) {
    char* ldsK = smem_ + grp * 16384 + buf * 8192;
    load_lds16(KgA, ldsK + oA);
    load_lds16(KgB, ldsK + oB);
    load_lds16(VgA, ldsK + 32768 + oA);
    load_lds16(VgB, ldsK + 32768 + oB);
    KgA += 8192; KgB += 8192; VgA += 128; VgB += 128;
  };

  stage(0);
  __syncthreads();

  #pragma unroll 1
  for (int it2 = 0; it2 < NTG / 2; ++it2) {
    stage(1);
    TILE(0, 32768);
    __syncthreads();
    if (it2 < NTG / 2 - 1) stage(0);
    TILE(8192, 40960);
    __syncthreads();
  }

  // ---- merge the two kv-halves (grp1 -> LDS -> grp0), then write ctx ----
  float l_own = xhalf_add(lsum);      // both halves' kv columns combined
  float* OL = (float*)smem_;          // [4 qs][64 d][32 q] f32 = 32 KiB (staging dead)
  float* ML = OL + 8192;              // m[4][32] then l[4][32]
  if (grp == 1) {
    #pragma unroll
    for (int g = 0; g < 4; ++g)
      #pragma unroll
      for (int j = 0; j < 4; ++j) {
        int d = 8 * g + 4 * hi + j;
        OL[(qs * 64 + d) * 32 + lane31]      = o0[4 * g + j];
        OL[(qs * 64 + 32 + d) * 32 + lane31] = o1[4 * g + j];
      }
    if (hi == 0) { ML[qs * 32 + lane31] = mr; ML[128 + qs * 32 + lane31] = l_own; }
  }
  __syncthreads();
  if (grp == 0) {
    float m1 = ML[qs * 32 + lane31], l1 = ML[128 + qs * 32 + lane31];
    float mm = fmaxf(mr, m1);
    float s0 = exp2v(mr - mm), s1 = exp2v(m1 - mm);
    float inv = 1.0f / (l_own * s0 + l1 * s1);
    __bf16* cp = ctx + (size_t)b * S_LEN * D_DIM + (size_t)q * D_DIM + (size_t)h * HDIM;
    #pragma unroll
    for (int g = 0; g < 4; ++g) {
      b4 v0, v1;
      #pragma unroll
      for (int j = 0; j < 4; ++j) {
        int d = 8 * g + 4 * hi + j;
        v0[j] = (__bf16)((o0[4 * g + j] * s0 + OL[(qs * 64 + d) * 32 + lane31] * s1) * inv);
        v1[j] = (__bf16)((o1[4 * g + j] * s0 + OL[(qs * 64 + 32 + d) * 32 + lane31] * s1) * inv);
      }
      int d0 = 8 * g + 4 * hi;
      *reinterpret_cast<b4*>(cp + d0)      = v0;
      *reinterpret_cast<b4*>(cp + 32 + d0) = v1;
    }
  }
}

// ===================== launch =====================
extern "C" void kernel_launch(void* const* d_in, const int* in_sizes, int n_in,
                              void* d_out, int out_size, void* d_ws, size_t ws_size,
                              hipStream_t stream) {
  const float* x  = (const float*)d_in[0];
  const float* Wq = (const float*)d_in[1];
  const float* bq = (const float*)d_in[2];
  const float* Wk = (const float*)d_in[3];
  const float* bk = (const float*)d_in[4];
  const float* Wv = (const float*)d_in[5];
  const float* bv = (const float*)d_in[6];
  const float* Wo = (const float*)d_in[7];
  const float* bo = (const float*)d_in[8];
  float* out = (float*)d_out;

  char* ws = (char*)d_ws;
  __bf16* xb   = (__bf16*)(ws);                               // 8192*512
  __bf16* wqb  = xb  + 4194304;                               // 512*512
  __bf16* wkb  = wqb + 262144;
  __bf16* wvb  = wkb + 262144;
  __bf16* wob  = wvb + 262144;
  __bf16* Qb   = wob + 262144;                                // 4*8*2048*64
  __bf16* Kb   = Qb  + 4194304;
  __bf16* Vtb  = Kb  + 4194304;                               // V transposed [B,H,HD,S]
  __bf16* ctxb = xb;  // reuse (x dead after QKV)

  cvt_kernel<<<dim3(4096), dim3(256), 0, stream>>>(x, xb);
  cvt_w_kernel<<<dim3(256, 4), dim3(256), 0, stream>>>(Wq, Wk, Wv, Wo, wqb, wkb, wvb, wob);
  gemm_qkv_kernel<<<dim3(128, 4, 3), dim3(256), 0, stream>>>(xb, wqb, wkb, wvb, bq, bk, bv, Qb, Kb, Vtb);
  attn_kernel<<<dim3(512), dim3(512), 0, stream>>>(Qb, Kb, Vtb, ctxb);
  gemm_o_kernel<<<dim3(128, 4), dim3(256), 0, stream>>>(ctxb, wob, bo, out);
}

// Round 17
// 90.298 us; speedup vs baseline: 1.0746x; 1.0117x over previous
//
#include <hip/hip_runtime.h>
#include <hip/hip_bf16.h>
#include <cstdint>
#include <cstddef>

// Problem dims (fixed): B=4, S=2048, D=512, H=8, HD=64, M = B*S = 8192
#define S_LEN 2048
#define D_DIM 512
#define NHEAD 8
#define HDIM  64

typedef __attribute__((ext_vector_type(8)))  __bf16 b8;    // MFMA A/B fragment (4 VGPRs)
typedef __attribute__((ext_vector_type(4)))  __bf16 b4;    // 8-byte vector
typedef __attribute__((ext_vector_type(4)))  float  f4;    // 16x16 C fragment
typedef __attribute__((ext_vector_type(16))) float  f16v;  // 32x32 C fragment
typedef __attribute__((ext_vector_type(4)))  unsigned int u32x4;

#define AS_GLOBAL __attribute__((address_space(1)))
#define AS_LDS    __attribute__((address_space(3)))

__device__ __forceinline__ void load_lds16(const void* g, void* l) {
  __builtin_amdgcn_global_load_lds((const AS_GLOBAL void*)g, (AS_LDS void*)l, 16, 0, 0);
}

__device__ __forceinline__ f4 mfma16(b8 a, b8 b, f4 c) {
  return __builtin_amdgcn_mfma_f32_16x16x32_bf16(a, b, c, 0, 0, 0);
}
__device__ __forceinline__ f16v mfma32(b8 a, b8 b, f16v c) {
  return __builtin_amdgcn_mfma_f32_32x32x16_bf16(a, b, c, 0, 0, 0);
}

// single-instruction 2^x
__device__ __forceinline__ float exp2v(float x) {
#if __has_builtin(__builtin_amdgcn_exp2f)
  return __builtin_amdgcn_exp2f(x);
#else
  float r; asm("v_exp_f32 %0, %1" : "=v"(r) : "v"(x)); return r;
#endif
}

// v_cvt_pk_bf16_f32: D.lo = bf16(S0), D.hi = bf16(S1)
__device__ __forceinline__ unsigned int pkbf(float lo, float hi_) {
  unsigned int r;
  asm("v_cvt_pk_bf16_f32 %0, %1, %2" : "=v"(r) : "v"(lo), "v"(hi_));
  return r;
}

// cross-half (lane i <-> lane i^32) combine. NOTE (R7/R8 post-mortem): a
// self-exchange via v_permlane32_swap inside one asm block reads stale
// registers; permlane is only safe in the MKFRAG pattern (distinct-value
// operands, compiler-scheduled producers). Use the proven shfl_xor forms.
__device__ __forceinline__ float xhalf_max(float v) {
  return fmaxf(v, __shfl_xor(v, 32));
}
__device__ __forceinline__ float xhalf_add(float v) {
  return v + __shfl_xor(v, 32);
}

// Swizzled read from an LDS tile with 128-byte rows. Physical byte =
// row*128 + (bytecol ^ ((row&7)<<4)); staging pre-applies the same XOR to the
// global source column so logical data lands in the right slot (involution).
__device__ __forceinline__ b8 lds_frag(const __bf16* base, int row, int bc) {
  return *reinterpret_cast<const b8*>((const char*)base + row * 128 + (bc ^ ((row & 7) << 4)));
}

// ===================== fp32 -> bf16 conversion =====================
__global__ __launch_bounds__(256) void cvt_kernel(const float* __restrict__ in,
                                                  __bf16* __restrict__ out) {
  int i = (blockIdx.x * 256 + threadIdx.x) * 4;
  float4 v = *reinterpret_cast<const float4*>(in + i);
  b4 o;
  o.x = (__bf16)v.x; o.y = (__bf16)v.y; o.z = (__bf16)v.z; o.w = (__bf16)v.w;
  *reinterpret_cast<b4*>(out + i) = o;
}

__global__ __launch_bounds__(256) void cvt_w_kernel(const float* __restrict__ w0, const float* __restrict__ w1,
                                                    const float* __restrict__ w2, const float* __restrict__ w3,
                                                    __bf16* o0, __bf16* o1, __bf16* o2, __bf16* o3) {
  const float* in = blockIdx.y == 0 ? w0 : blockIdx.y == 1 ? w1 : blockIdx.y == 2 ? w2 : w3;
  __bf16* out     = blockIdx.y == 0 ? o0 : blockIdx.y == 1 ? o1 : blockIdx.y == 2 ? o2 : o3;
  int i = (blockIdx.x * 256 + threadIdx.x) * 4;
  float4 v = *reinterpret_cast<const float4*>(in + i);
  b4 o;
  o.x = (__bf16)v.x; o.y = (__bf16)v.y; o.z = (__bf16)v.z; o.w = (__bf16)v.w;
  *reinterpret_cast<b4*>(out + i) = o;
}

// ============ 2-phase double-buffered GEMM core: C(64x128) = A * W^T =========
// Attn-style pipeline: stage K-step t+1 into buf^1 BEFORE computing buf, one
// barrier per K-step (serves both "staged done" and "reads done"). LDS 48 KB
// -> 3 blocks/CU; staging latency hidden under MFMA within the block.
// Buffers: A at [buf*8192, +8KB), B at 16384 + buf*16384 (+16KB).
__device__ __forceinline__ void gemm_core_db(const __bf16* __restrict__ A, const __bf16* __restrict__ W,
                                             int m0, int n0, char* sm, f4 acc[2][4]) {
  const int t = threadIdx.x;
  const int lane = t & 63;
  const int w = t >> 6, wr = w >> 1, wc = w & 1;
  const f4 zero = {0.f, 0.f, 0.f, 0.f};
  #pragma unroll
  for (int mi = 0; mi < 2; ++mi)
    #pragma unroll
    for (int ni = 0; ni < 4; ++ni) acc[mi][ni] = zero;

  // hoisted staging addresses (advance 128 B per K-step)
  int oA = t * 16;                      // 0..4080
  int rA = oA >> 7, cbA = oA & 127;
  int sAo = cbA ^ ((rA & 7) << 4);
  const char* Ag0 = (const char*)A + ((size_t)(m0 + rA) * 512) * 2 + sAo;          // A rows 0-31
  const char* Ag1 = (const char*)A + ((size_t)(m0 + 32 + rA) * 512) * 2 + sAo;     // A rows 32-63
  const char* Wg0 = (const char*)W + ((size_t)(n0 + rA) * 512) * 2 + sAo;          // W rows 0-31
  const char* Wg1 = (const char*)W + ((size_t)(n0 + 32 + rA) * 512) * 2 + sAo;
  const char* Wg2 = (const char*)W + ((size_t)(n0 + 64 + rA) * 512) * 2 + sAo;
  const char* Wg3 = (const char*)W + ((size_t)(n0 + 96 + rA) * 512) * 2 + sAo;

  auto stage = [&](int buf) {
    char* la = sm + buf * 8192;
    char* lb = sm + 16384 + buf * 16384;
    load_lds16(Ag0, la + oA);
    load_lds16(Ag1, la + 4096 + oA);
    load_lds16(Wg0, lb + oA);
    load_lds16(Wg1, lb + 4096 + oA);
    load_lds16(Wg2, lb + 8192 + oA);
    load_lds16(Wg3, lb + 12288 + oA);
    Ag0 += 128; Ag1 += 128; Wg0 += 128; Wg1 += 128; Wg2 += 128; Wg3 += 128;
  };

  stage(0);
  __syncthreads();          // buf0 ready
  int cur = 0;
  #pragma unroll 1
  for (int ks = 0; ks < 8; ++ks) {
    if (ks < 7) stage(cur ^ 1);     // prefetch next K-step
    const __bf16* As = (const __bf16*)(sm + cur * 8192);
    const __bf16* Bs = (const __bf16*)(sm + 16384 + cur * 16384);
    #pragma unroll
    for (int kk = 0; kk < 2; ++kk) {
      b8 af[2], bf[4];
      #pragma unroll
      for (int mi = 0; mi < 2; ++mi)
        af[mi] = lds_frag(As, wr * 32 + mi * 16 + (lane & 15), kk * 64 + ((lane >> 4) << 4));
      #pragma unroll
      for (int ni = 0; ni < 4; ++ni)
        bf[ni] = lds_frag(Bs, wc * 64 + ni * 16 + (lane & 15), kk * 64 + ((lane >> 4) << 4));
      #pragma unroll
      for (int mi = 0; mi < 2; ++mi)
        #pragma unroll
        for (int ni = 0; ni < 4; ++ni)
          acc[mi][ni] = mfma16(af[mi], bf[ni], acc[mi][ni]);
    }
    __syncthreads();        // next buf staged + all waves done reading cur
    cur ^= 1;
  }
}

// ===================== GEMM core (single-buffered, R13-proven; gemm_o) ========
__device__ __forceinline__ void gemm_core(const __bf16* __restrict__ A, const __bf16* __restrict__ W,
                                          int m0, int n0, __bf16* As, __bf16* Bs, f4 acc[2][4]) {
  const int t = threadIdx.x;
  const int lane = t & 63;
  const int w = t >> 6, wr = w >> 1, wc = w & 1;
  const f4 zero = {0.f, 0.f, 0.f, 0.f};
  #pragma unroll
  for (int mi = 0; mi < 2; ++mi)
    #pragma unroll
    for (int ni = 0; ni < 4; ++ni) acc[mi][ni] = zero;

  const char* Ab = (const char*)A;
  const char* Wb = (const char*)W;
  for (int kt = 0; kt < 512; kt += 64) {
    __syncthreads();
    #pragma unroll
    for (int i = 0; i < 2; ++i) {        // A tile: 64x64 bf16 = 8 KB
      int o = i * 4096 + t * 16;
      int row = o >> 7, cb = o & 127;
      int scb = cb ^ ((row & 7) << 4);
      load_lds16(Ab + ((size_t)(m0 + row) * 512 + kt) * 2 + scb, (char*)As + o);
    }
    #pragma unroll
    for (int i = 0; i < 4; ++i) {        // B tile: 128x64 bf16 = 16 KB
      int o = i * 4096 + t * 16;
      int row = o >> 7, cb = o & 127;
      int scb = cb ^ ((row & 7) << 4);
      load_lds16(Wb + ((size_t)(n0 + row) * 512 + kt) * 2 + scb, (char*)Bs + o);
    }
    __syncthreads();
    #pragma unroll
    for (int kk = 0; kk < 2; ++kk) {
      b8 af[2], bf[4];
      #pragma unroll
      for (int mi = 0; mi < 2; ++mi)
        af[mi] = lds_frag(As, wr * 32 + mi * 16 + (lane & 15), kk * 64 + ((lane >> 4) << 4));
      #pragma unroll
      for (int ni = 0; ni < 4; ++ni)
        bf[ni] = lds_frag(Bs, wc * 64 + ni * 16 + (lane & 15), kk * 64 + ((lane >> 4) << 4));
      #pragma unroll
      for (int mi = 0; mi < 2; ++mi)
        #pragma unroll
        for (int ni = 0; ni < 4; ++ni)
          acc[mi][ni] = mfma16(af[mi], bf[ni], acc[mi][ni]);
    }
  }
}

// ===================== QKV projection (2-phase dbuf core) =====================
// grid (128, 4, 3); z picks {Wq,Wk,Wv}. Q,K written [B,H,S,HD]; V written
// TRANSPOSED [B,H,HD,S] directly in the epilogue.
// Q pre-scaled by (1/sqrt(dk))*log2(e) so attention exp runs in base-2 domain.
__global__ __launch_bounds__(256) void gemm_qkv_kernel(
    const __bf16* __restrict__ xb,
    const __bf16* __restrict__ wq, const __bf16* __restrict__ wk, const __bf16* __restrict__ wv,
    const float* __restrict__ bq, const float* __restrict__ bk, const float* __restrict__ bv,
    __bf16* Qo, __bf16* Ko, __bf16* Vto) {
  __shared__ char sm[49152];   // A dbuf 16 KB + B dbuf 32 KB
  int z = blockIdx.z;
  const __bf16* W = z == 0 ? wq : (z == 1 ? wk : wv);
  const float* bias = z == 0 ? bq : (z == 1 ? bk : bv);
  const float sc = (z == 0) ? 0.18033688011112042f : 1.0f;  // 0.125 * log2(e)
  int m0 = blockIdx.x * 64, n0 = blockIdx.y * 128;
  f4 acc[2][4];
  gemm_core_db(xb, W, m0, n0, sm, acc);
  int t = threadIdx.x, lane = t & 63, w = t >> 6, wr = w >> 1, wc = w & 1;
  if (z == 2) {
    // V^T epilogue: [B,H,HD,S]; r=0..3 -> s0..s0+3 at fixed hd -> b4 store.
    #pragma unroll
    for (int mi = 0; mi < 2; ++mi)
      #pragma unroll
      for (int ni = 0; ni < 4; ++ni) {
        int m = m0 + wr * 32 + mi * 16 + ((lane >> 4) << 2);   // r=0 row
        int n = n0 + wc * 64 + ni * 16 + (lane & 15);
        float bv_ = bias[n];
        b4 v;
        #pragma unroll
        for (int r = 0; r < 4; ++r) v[r] = (__bf16)(acc[mi][ni][r] + bv_);
        int b = m >> 11, s = m & 2047, h = n >> 6, hd = n & 63;
        *reinterpret_cast<b4*>(&Vto[(((size_t)(b * NHEAD + h)) * HDIM + hd) * S_LEN + s]) = v;
      }
  } else {
    __bf16* out = z == 0 ? Qo : Ko;
    #pragma unroll
    for (int mi = 0; mi < 2; ++mi)
      #pragma unroll
      for (int ni = 0; ni < 4; ++ni)
        #pragma unroll
        for (int r = 0; r < 4; ++r) {
          int m = m0 + wr * 32 + mi * 16 + ((lane >> 4) << 2) + r;
          int n = n0 + wc * 64 + ni * 16 + (lane & 15);
          float v = (acc[mi][ni][r] + bias[n]) * sc;
          int b = m >> 11, s = m & 2047, h = n >> 6, hd = n & 63;
          out[(((size_t)(b * NHEAD + h)) * S_LEN + s) * HDIM + hd] = (__bf16)v;
        }
  }
}

// ===================== output projection (R13-proven config) ==================
__global__ __launch_bounds__(256) void gemm_o_kernel(const __bf16* __restrict__ ctx,
                                                     const __bf16* __restrict__ wo,
                                                     const float* __restrict__ bo,
                                                     float* __restrict__ out) {
  __shared__ __bf16 As[64 * 64];
  __shared__ __bf16 Bs[128 * 64];
  int m0 = blockIdx.x * 64, n0 = blockIdx.y * 128;
  f4 acc[2][4];
  gemm_core(ctx, wo, m0, n0, As, Bs, acc);
  int t = threadIdx.x, lane = t & 63, w = t >> 6, wr = w >> 1, wc = w & 1;
  #pragma unroll
  for (int mi = 0; mi < 2; ++mi)
    #pragma unroll
    for (int ni = 0; ni < 4; ++ni)
      #pragma unroll
      for (int r = 0; r < 4; ++r) {
        int m = m0 + wr * 32 + mi * 16 + ((lane >> 4) << 2) + r;
        int n = n0 + wc * 64 + ni * 16 + (lane & 15);
        out[(size_t)m * D_DIM + n] = acc[mi][ni][r] + bo[n];
      }
}

// ===================== flash attention (kv-split-2, 8 waves) =====================
// R9 structure + conditional cross-half exchange. NOTE: the constant
// SQ_LDS_BANK_CONFLICT=4194304 is intrinsic ds_read_b128 overhead
// (1048576 reads x 4 cy; m134: b128 ~12cy vs 8 ideal), NOT a fixable conflict.
// Occupancy pinned: ~128 VGPR/wave -> 16 waves/CU; LDS 64 KB -> 2 blocks/CU.
#define NTG 16  // kv tiles per group: 1024 / 64

// Build PV B-fragment for one 16-k slot from C-layout f32 P regs base..base+7.
// v_permlane32_swap_b32: vdst.lanes[32:63] <-> vsrc.lanes[0:31]. swap(A0,B0):
//   lo lane: A0 = A0_own,     B0 = A0 from hi partner
//   hi lane: A0 = B0 from lo, B0 = B0_own
// -> fragment words [A0, A1, B0, B1] for both halves. (Producers are separate
// asm blocks; compiler scheduling provides the permlane hazard distance.)
#define MKFRAG(dst, st, base) do {                                   \
    unsigned int A0_ = pkbf((st)[(base)+0], (st)[(base)+1]);         \
    unsigned int A1_ = pkbf((st)[(base)+2], (st)[(base)+3]);         \
    unsigned int B0_ = pkbf((st)[(base)+4], (st)[(base)+5]);         \
    unsigned int B1_ = pkbf((st)[(base)+6], (st)[(base)+7]);         \
    asm("v_permlane32_swap_b32 %0, %1" : "+v"(A0_), "+v"(B0_));      \
    asm("v_permlane32_swap_b32 %0, %1" : "+v"(A1_), "+v"(B1_));      \
    u32x4 wv_; wv_.x = A0_; wv_.y = A1_; wv_.z = B0_; wv_.w = B1_;   \
    dst = __builtin_bit_cast(b8, wv_);                               \
  } while (0)

// One 64-kv tile. KO/VO are compile-time byte offsets of the K / V tiles.
#define TILE(KO, VO) do {                                                     \
    f16v t0 = Z16, t1 = Z16;                                                  \
    __builtin_amdgcn_s_setprio(1);                                            \
    _Pragma("unroll")                                                         \
    for (int ks = 0; ks < 4; ++ks) {                                          \
      b8 kf0 = *reinterpret_cast<const AS_LDS b8*>(sb + koff[ks] + (KO));     \
      b8 kf1 = *reinterpret_cast<const AS_LDS b8*>(sb + koff[ks] + (KO) + 4096); \
      t0 = mfma32(kf0, qf[ks], t0);                                           \
      t1 = mfma32(kf1, qf[ks], t1);                                           \
    }                                                                         \
    __builtin_amdgcn_s_setprio(0);                                            \
    float a0 = fmaxf(fmaxf(t0[0], t0[8]),  fmaxf(t1[0], t1[8]));              \
    float a1 = fmaxf(fmaxf(t0[1], t0[9]),  fmaxf(t1[1], t1[9]));              \
    float a2 = fmaxf(fmaxf(t0[2], t0[10]), fmaxf(t1[2], t1[10]));             \
    float a3 = fmaxf(fmaxf(t0[3], t0[11]), fmaxf(t1[3], t1[11]));             \
    float a4 = fmaxf(fmaxf(t0[4], t0[12]), fmaxf(t1[4], t1[12]));             \
    float a5 = fmaxf(fmaxf(t0[5], t0[13]), fmaxf(t1[5], t1[13]));             \
    float a6 = fmaxf(fmaxf(t0[6], t0[14]), fmaxf(t1[6], t1[14]));             \
    float a7 = fmaxf(fmaxf(t0[7], t0[15]), fmaxf(t1[7], t1[15]));             \
    float mx = fmaxf(fmaxf(fmaxf(a0, a1), fmaxf(a2, a3)),                     \
                     fmaxf(fmaxf(a4, a5), fmaxf(a6, a7)));                    \
    if (!__all(mx - mr <= 11.5f)) {                                           \
      mx = xhalf_max(mx);              /* true global max (rare path) */      \
      float mn = fmaxf(mr, mx);                                               \
      float al = exp2v(mr - mn);                                              \
      mr = mn; lsum *= al; o0 *= al; o1 *= al;                                \
    }                                                                         \
    _Pragma("unroll")                                                         \
    for (int r = 0; r < 16; ++r) t0[r] = exp2v(t0[r] - mr);                   \
    _Pragma("unroll")                                                         \
    for (int r = 0; r < 16; ++r) t1[r] = exp2v(t1[r] - mr);                   \
    {                                                                         \
      float p0 = (t0[0] + t1[0]) + (t0[8]  + t1[8]);                          \
      float p1 = (t0[1] + t1[1]) + (t0[9]  + t1[9]);                          \
      float p2 = (t0[2] + t1[2]) + (t0[10] + t1[10]);                         \
      float p3 = (t0[3] + t1[3]) + (t0[11] + t1[11]);                         \
      float p4 = (t0[4] + t1[4]) + (t0[12] + t1[12]);                         \
      float p5 = (t0[5] + t1[5]) + (t0[13] + t1[13]);                         \
      float p6 = (t0[6] + t1[6]) + (t0[14] + t1[14]);                         \
      float p7 = (t0[7] + t1[7]) + (t0[15] + t1[15]);                         \
      lsum += ((p0 + p1) + (p2 + p3)) + ((p4 + p5) + (p6 + p7));              \
    }                                                                         \
    __builtin_amdgcn_s_setprio(1);                                            \
    _Pragma("unroll")                                                         \
    for (int ks = 0; ks < 4; ++ks) {                                          \
      b8 pa;                                                                  \
      if (ks == 0)      MKFRAG(pa, t0, 0);                                    \
      else if (ks == 1) MKFRAG(pa, t0, 8);                                    \
      else if (ks == 2) MKFRAG(pa, t1, 0);                                    \
      else              MKFRAG(pa, t1, 8);                                    \
      b8 vf0 = *reinterpret_cast<const AS_LDS b8*>(sb + koff[ks] + (VO));     \
      b8 vf1 = *reinterpret_cast<const AS_LDS b8*>(sb + koff[ks] + (VO) + 4096); \
      o0 = mfma32(vf0, pa, o0);                                               \
      o1 = mfma32(vf1, pa, o1);                                               \
    }                                                                         \
    __builtin_amdgcn_s_setprio(0);                                            \
  } while (0)

__global__ __launch_bounds__(512, 4) void attn_kernel(const __bf16* __restrict__ Q,
                                                      const __bf16* __restrict__ K,
                                                      const __bf16* __restrict__ Vt,
                                                      __bf16* __restrict__ ctx) {
  __shared__ char smem_[65536];
  int t = threadIdx.x, lane = t & 63, w = t >> 6;
  int lane31 = lane & 31, hi = lane >> 5;
  int grp = w >> 2, qs = w & 3, t256 = t & 255;

  // XCD swizzle: 512 blocks, 8 XCDs -> 64-block contiguous chunk per XCD
  // = 4 whole heads per XCD (16 q-tiles x same bh -> K/V L2-resident).
  int bid = blockIdx.x;
  int nid = (bid & 7) * 64 + (bid >> 3);
  int bh = nid >> 4, qtile = nid & 15;
  int b = bh >> 3, h = bh & 7;
  int q = qtile * 128 + qs * 32 + lane31;   // this lane's q row
  const __bf16* Qp = Q + (size_t)bh * S_LEN * HDIM;
  const __bf16* Kp = K + (size_t)bh * S_LEN * HDIM;
  const __bf16* Vp = Vt + (size_t)bh * HDIM * S_LEN;
  const int kv0 = grp * (S_LEN / 2);

  // Q fragments (B-operand: col=q=lane31, k=d=ks*16+hi*8+e). Q pre-scaled.
  b8 qf[4];
  #pragma unroll
  for (int ks = 0; ks < 4; ++ks)
    qf[ks] = *reinterpret_cast<const b8*>(&Qp[(size_t)q * HDIM + ks * 16 + hi * 8]);

  // 32-bit LDS base + per-ks fragment offsets (half1 = +4096 immediate since
  // (row+32)&7 == row&7). koff folds in grp*16384.
  const AS_LDS char* sb = (const AS_LDS char*)smem_;
  unsigned koff[4];
  #pragma unroll
  for (int ks = 0; ks < 4; ++ks) {
    int bc = hi * 16 + ks * 32;
    koff[ks] = grp * 16384 + lane31 * 128 + (bc ^ ((lane31 & 7) << 4));
  }

  // staging addresses (strength-reduced per iteration)
  int oA = t256 * 16, oB = 4096 + t256 * 16;
  int rA = oA >> 7, rB = oB >> 7;
  int sA = (oA & 127) ^ ((rA & 7) << 4), sB = (oB & 127) ^ ((rB & 7) << 4);
  const char* KgA = (const char*)Kp + (size_t)(kv0 + rA) * 128 + sA;   // += 8192/iter
  const char* KgB = (const char*)Kp + (size_t)(kv0 + rB) * 128 + sB;
  const char* VgA = (const char*)Vp + (size_t)rA * (S_LEN * 2) + (size_t)kv0 * 2 + sA;  // += 128/iter
  const char* VgB = (const char*)Vp + (size_t)rB * (S_LEN * 2) + (size_t)kv0 * 2 + sB;

  const f16v Z16 = {0,0,0,0,0,0,0,0,0,0,0,0,0,0,0,0};
  f16v o0 = Z16, o1 = Z16;   // O^T accum: rows d (0-31 / 32-63), col q
  float mr = -1e30f, lsum = 0.f;

  auto stage = [&](int buf) {
    char* ldsK = smem_ + grp * 16384 + buf * 8192;
    load_lds16(KgA, ldsK + oA);
    load_lds16(KgB, ldsK + oB);
    load_lds16(VgA, ldsK + 32768 + oA);
    load_lds16(VgB, ldsK + 32768 + oB);
    KgA += 8192; KgB += 8192; VgA += 128; VgB += 128;
  };

  stage(0);
  __syncthreads();

  #pragma unroll 1
  for (int it2 = 0; it2 < NTG / 2; ++it2) {
    stage(1);
    TILE(0, 32768);
    __syncthreads();
    if (it2 < NTG / 2 - 1) stage(0);
    TILE(8192, 40960);
    __syncthreads();
  }

  // ---- merge the two kv-halves (grp1 -> LDS -> grp0), then write ctx ----
  float l_own = xhalf_add(lsum);      // both halves' kv columns combined
  float* OL = (float*)smem_;          // [4 qs][64 d][32 q] f32 = 32 KiB (staging dead)
  float* ML = OL + 8192;              // m[4][32] then l[4][32]
  if (grp == 1) {
    #pragma unroll
    for (int g = 0; g < 4; ++g)
      #pragma unroll
      for (int j = 0; j < 4; ++j) {
        int d = 8 * g + 4 * hi + j;
        OL[(qs * 64 + d) * 32 + lane31]      = o0[4 * g + j];
        OL[(qs * 64 + 32 + d) * 32 + lane31] = o1[4 * g + j];
      }
    if (hi == 0) { ML[qs * 32 + lane31] = mr; ML[128 + qs * 32 + lane31] = l_own; }
  }
  __syncthreads();
  if (grp == 0) {
    float m1 = ML[qs * 32 + lane31], l1 = ML[128 + qs * 32 + lane31];
    float mm = fmaxf(mr, m1);
    float s0 = exp2v(mr - mm), s1 = exp2v(m1 - mm);
    float inv = 1.0f / (l_own * s0 + l1 * s1);
    __bf16* cp = ctx + (size_t)b * S_LEN * D_DIM + (size_t)q * D_DIM + (size_t)h * HDIM;
    #pragma unroll
    for (int g = 0; g < 4; ++g) {
      b4 v0, v1;
      #pragma unroll
      for (int j = 0; j < 4; ++j) {
        int d = 8 * g + 4 * hi + j;
        v0[j] = (__bf16)((o0[4 * g + j] * s0 + OL[(qs * 64 + d) * 32 + lane31] * s1) * inv);
        v1[j] = (__bf16)((o1[4 * g + j] * s0 + OL[(qs * 64 + 32 + d) * 32 + lane31] * s1) * inv);
      }
      int d0 = 8 * g + 4 * hi;
      *reinterpret_cast<b4*>(cp + d0)      = v0;
      *reinterpret_cast<b4*>(cp + 32 + d0) = v1;
    }
  }
}

// ===================== launch =====================
extern "C" void kernel_launch(void* const* d_in, const int* in_sizes, int n_in,
                              void* d_out, int out_size, void* d_ws, size_t ws_size,
                              hipStream_t stream) {
  const float* x  = (const float*)d_in[0];
  const float* Wq = (const float*)d_in[1];
  const float* bq = (const float*)d_in[2];
  const float* Wk = (const float*)d_in[3];
  const float* bk = (const float*)d_in[4];
  const float* Wv = (const float*)d_in[5];
  const float* bv = (const float*)d_in[6];
  const float* Wo = (const float*)d_in[7];
  const float* bo = (const float*)d_in[8];
  float* out = (float*)d_out;

  char* ws = (char*)d_ws;
  __bf16* xb   = (__bf16*)(ws);                               // 8192*512
  __bf16* wqb  = xb  + 4194304;                               // 512*512
  __bf16* wkb  = wqb + 262144;
  __bf16* wvb  = wkb + 262144;
  __bf16* wob  = wvb + 262144;
  __bf16* Qb   = wob + 262144;                                // 4*8*2048*64
  __bf16* Kb   = Qb  + 4194304;
  __bf16* Vtb  = Kb  + 4194304;                               // V transposed [B,H,HD,S]
  __bf16* ctxb = xb;  // reuse (x dead after QKV)

  cvt_kernel<<<dim3(4096), dim3(256), 0, stream>>>(x, xb);
  cvt_w_kernel<<<dim3(256, 4), dim3(256), 0, stream>>>(Wq, Wk, Wv, Wo, wqb, wkb, wvb, wob);
  gemm_qkv_kernel<<<dim3(128, 4, 3), dim3(256), 0, stream>>>(xb, wqb, wkb, wvb, bq, bk, bv, Qb, Kb, Vtb);
  attn_kernel<<<dim3(512), dim3(512), 0, stream>>>(Qb, Kb, Vtb, ctxb);
  gemm_o_kernel<<<dim3(128, 4), dim3(256), 0, stream>>>(ctxb, wob, bo, out);
}

// Round 18
// 89.584 us; speedup vs baseline: 1.0832x; 1.0080x over previous
//
#include <hip/hip_runtime.h>
#include <hip/hip_bf16.h>
#include <cstdint>
#include <cstddef>

// Problem dims (fixed): B=4, S=2048, D=512, H=8, HD=64, M = B*S = 8192
#define S_LEN 2048
#define D_DIM 512
#define NHEAD 8
#define HDIM  64

typedef __attribute__((ext_vector_type(8)))  __bf16 b8;    // MFMA A/B fragment (4 VGPRs)
typedef __attribute__((ext_vector_type(4)))  __bf16 b4;    // 8-byte vector
typedef __attribute__((ext_vector_type(4)))  float  f4;    // 16x16 C fragment
typedef __attribute__((ext_vector_type(16))) float  f16v;  // 32x32 C fragment
typedef __attribute__((ext_vector_type(4)))  unsigned int u32x4;

#define AS_GLOBAL __attribute__((address_space(1)))
#define AS_LDS    __attribute__((address_space(3)))

__device__ __forceinline__ void load_lds16(const void* g, void* l) {
  __builtin_amdgcn_global_load_lds((const AS_GLOBAL void*)g, (AS_LDS void*)l, 16, 0, 0);
}

__device__ __forceinline__ f4 mfma16(b8 a, b8 b, f4 c) {
  return __builtin_amdgcn_mfma_f32_16x16x32_bf16(a, b, c, 0, 0, 0);
}
__device__ __forceinline__ f16v mfma32(b8 a, b8 b, f16v c) {
  return __builtin_amdgcn_mfma_f32_32x32x16_bf16(a, b, c, 0, 0, 0);
}

// single-instruction 2^x
__device__ __forceinline__ float exp2v(float x) {
#if __has_builtin(__builtin_amdgcn_exp2f)
  return __builtin_amdgcn_exp2f(x);
#else
  float r; asm("v_exp_f32 %0, %1" : "=v"(r) : "v"(x)); return r;
#endif
}

// v_cvt_pk_bf16_f32: D.lo = bf16(S0), D.hi = bf16(S1)
__device__ __forceinline__ unsigned int pkbf(float lo, float hi_) {
  unsigned int r;
  asm("v_cvt_pk_bf16_f32 %0, %1, %2" : "=v"(r) : "v"(lo), "v"(hi_));
  return r;
}

// cross-half (lane i <-> lane i^32) combine. NOTE (R7/R8 post-mortem): a
// self-exchange via v_permlane32_swap inside one asm block reads stale
// registers; permlane is only safe in the MKFRAG pattern (distinct-value
// operands, compiler-scheduled producers). Use the proven shfl_xor forms.
__device__ __forceinline__ float xhalf_max(float v) {
  return fmaxf(v, __shfl_xor(v, 32));
}
__device__ __forceinline__ float xhalf_add(float v) {
  return v + __shfl_xor(v, 32);
}

// Swizzled read from an LDS tile with 128-byte rows. Physical byte =
// row*128 + (bytecol ^ ((row&7)<<4)); staging pre-applies the same XOR to the
// global source column so logical data lands in the right slot (involution).
__device__ __forceinline__ b8 lds_frag(const __bf16* base, int row, int bc) {
  return *reinterpret_cast<const b8*>((const char*)base + row * 128 + (bc ^ ((row & 7) << 4)));
}

// ===================== fp32 -> bf16 conversion =====================
__global__ __launch_bounds__(256) void cvt_kernel(const float* __restrict__ in,
                                                  __bf16* __restrict__ out) {
  int i = (blockIdx.x * 256 + threadIdx.x) * 4;
  float4 v = *reinterpret_cast<const float4*>(in + i);
  b4 o;
  o.x = (__bf16)v.x; o.y = (__bf16)v.y; o.z = (__bf16)v.z; o.w = (__bf16)v.w;
  *reinterpret_cast<b4*>(out + i) = o;
}

__global__ __launch_bounds__(256) void cvt_w_kernel(const float* __restrict__ w0, const float* __restrict__ w1,
                                                    const float* __restrict__ w2, const float* __restrict__ w3,
                                                    __bf16* o0, __bf16* o1, __bf16* o2, __bf16* o3) {
  const float* in = blockIdx.y == 0 ? w0 : blockIdx.y == 1 ? w1 : blockIdx.y == 2 ? w2 : w3;
  __bf16* out     = blockIdx.y == 0 ? o0 : blockIdx.y == 1 ? o1 : blockIdx.y == 2 ? o2 : o3;
  int i = (blockIdx.x * 256 + threadIdx.x) * 4;
  float4 v = *reinterpret_cast<const float4*>(in + i);
  b4 o;
  o.x = (__bf16)v.x; o.y = (__bf16)v.y; o.z = (__bf16)v.z; o.w = (__bf16)v.w;
  *reinterpret_cast<b4*>(out + i) = o;
}

// ============ 2-phase double-buffered GEMM core: C(64x128) = A * W^T =========
// Attn-style pipeline: stage K-step t+1 into buf^1 BEFORE computing buf, one
// barrier per K-step (serves both "staged done" and "reads done"). LDS 48 KB.
// Buffers: A at [buf*8192, +8KB), B at 16384 + buf*16384 (+16KB).
__device__ __forceinline__ void gemm_core_db(const __bf16* __restrict__ A, const __bf16* __restrict__ W,
                                             int m0, int n0, char* sm, f4 acc[2][4]) {
  const int t = threadIdx.x;
  const int lane = t & 63;
  const int w = t >> 6, wr = w >> 1, wc = w & 1;
  const f4 zero = {0.f, 0.f, 0.f, 0.f};
  #pragma unroll
  for (int mi = 0; mi < 2; ++mi)
    #pragma unroll
    for (int ni = 0; ni < 4; ++ni) acc[mi][ni] = zero;

  // hoisted staging addresses (advance 128 B per K-step)
  int oA = t * 16;                      // 0..4080
  int rA = oA >> 7, cbA = oA & 127;
  int sAo = cbA ^ ((rA & 7) << 4);
  const char* Ag0 = (const char*)A + ((size_t)(m0 + rA) * 512) * 2 + sAo;          // A rows 0-31
  const char* Ag1 = (const char*)A + ((size_t)(m0 + 32 + rA) * 512) * 2 + sAo;     // A rows 32-63
  const char* Wg0 = (const char*)W + ((size_t)(n0 + rA) * 512) * 2 + sAo;          // W rows 0-31
  const char* Wg1 = (const char*)W + ((size_t)(n0 + 32 + rA) * 512) * 2 + sAo;
  const char* Wg2 = (const char*)W + ((size_t)(n0 + 64 + rA) * 512) * 2 + sAo;
  const char* Wg3 = (const char*)W + ((size_t)(n0 + 96 + rA) * 512) * 2 + sAo;

  auto stage = [&](int buf) {
    char* la = sm + buf * 8192;
    char* lb = sm + 16384 + buf * 16384;
    load_lds16(Ag0, la + oA);
    load_lds16(Ag1, la + 4096 + oA);
    load_lds16(Wg0, lb + oA);
    load_lds16(Wg1, lb + 4096 + oA);
    load_lds16(Wg2, lb + 8192 + oA);
    load_lds16(Wg3, lb + 12288 + oA);
    Ag0 += 128; Ag1 += 128; Wg0 += 128; Wg1 += 128; Wg2 += 128; Wg3 += 128;
  };

  stage(0);
  __syncthreads();          // buf0 ready
  int cur = 0;
  #pragma unroll 1
  for (int ks = 0; ks < 8; ++ks) {
    if (ks < 7) stage(cur ^ 1);     // prefetch next K-step
    const __bf16* As = (const __bf16*)(sm + cur * 8192);
    const __bf16* Bs = (const __bf16*)(sm + 16384 + cur * 16384);
    #pragma unroll
    for (int kk = 0; kk < 2; ++kk) {
      b8 af[2], bf[4];
      #pragma unroll
      for (int mi = 0; mi < 2; ++mi)
        af[mi] = lds_frag(As, wr * 32 + mi * 16 + (lane & 15), kk * 64 + ((lane >> 4) << 4));
      #pragma unroll
      for (int ni = 0; ni < 4; ++ni)
        bf[ni] = lds_frag(Bs, wc * 64 + ni * 16 + (lane & 15), kk * 64 + ((lane >> 4) << 4));
      #pragma unroll
      for (int mi = 0; mi < 2; ++mi)
        #pragma unroll
        for (int ni = 0; ni < 4; ++ni)
          acc[mi][ni] = mfma16(af[mi], bf[ni], acc[mi][ni]);
    }
    __syncthreads();        // next buf staged + all waves done reading cur
    cur ^= 1;
  }
}

// ===================== QKV projection (2-phase dbuf core) =====================
// grid (128, 4, 3); z picks {Wq,Wk,Wv}. Q,K written [B,H,S,HD]; V written
// TRANSPOSED [B,H,HD,S] directly in the epilogue.
// Q pre-scaled by (1/sqrt(dk))*log2(e) so attention exp runs in base-2 domain.
__global__ __launch_bounds__(256) void gemm_qkv_kernel(
    const __bf16* __restrict__ xb,
    const __bf16* __restrict__ wq, const __bf16* __restrict__ wk, const __bf16* __restrict__ wv,
    const float* __restrict__ bq, const float* __restrict__ bk, const float* __restrict__ bv,
    __bf16* Qo, __bf16* Ko, __bf16* Vto) {
  __shared__ char sm[49152];   // A dbuf 16 KB + B dbuf 32 KB
  int z = blockIdx.z;
  const __bf16* W = z == 0 ? wq : (z == 1 ? wk : wv);
  const float* bias = z == 0 ? bq : (z == 1 ? bk : bv);
  const float sc = (z == 0) ? 0.18033688011112042f : 1.0f;  // 0.125 * log2(e)
  int m0 = blockIdx.x * 64, n0 = blockIdx.y * 128;
  f4 acc[2][4];
  gemm_core_db(xb, W, m0, n0, sm, acc);
  int t = threadIdx.x, lane = t & 63, w = t >> 6, wr = w >> 1, wc = w & 1;
  if (z == 2) {
    // V^T epilogue: [B,H,HD,S]; r=0..3 -> s0..s0+3 at fixed hd -> b4 store.
    #pragma unroll
    for (int mi = 0; mi < 2; ++mi)
      #pragma unroll
      for (int ni = 0; ni < 4; ++ni) {
        int m = m0 + wr * 32 + mi * 16 + ((lane >> 4) << 2);   // r=0 row
        int n = n0 + wc * 64 + ni * 16 + (lane & 15);
        float bv_ = bias[n];
        b4 v;
        #pragma unroll
        for (int r = 0; r < 4; ++r) v[r] = (__bf16)(acc[mi][ni][r] + bv_);
        int b = m >> 11, s = m & 2047, h = n >> 6, hd = n & 63;
        *reinterpret_cast<b4*>(&Vto[(((size_t)(b * NHEAD + h)) * HDIM + hd) * S_LEN + s]) = v;
      }
  } else {
    __bf16* out = z == 0 ? Qo : Ko;
    #pragma unroll
    for (int mi = 0; mi < 2; ++mi)
      #pragma unroll
      for (int ni = 0; ni < 4; ++ni)
        #pragma unroll
        for (int r = 0; r < 4; ++r) {
          int m = m0 + wr * 32 + mi * 16 + ((lane >> 4) << 2) + r;
          int n = n0 + wc * 64 + ni * 16 + (lane & 15);
          float v = (acc[mi][ni][r] + bias[n]) * sc;
          int b = m >> 11, s = m & 2047, h = n >> 6, hd = n & 63;
          out[(((size_t)(b * NHEAD + h)) * S_LEN + s) * HDIM + hd] = (__bf16)v;
        }
  }
}

// ===================== output projection (2-phase dbuf core) ==================
// grid (128,4) = 512 blocks = 2 blocks/CU (grid-capped either way, so the
// 48 KB dbuf costs no occupancy here — pure barrier/pipeline upside).
__global__ __launch_bounds__(256) void gemm_o_kernel(const __bf16* __restrict__ ctx,
                                                     const __bf16* __restrict__ wo,
                                                     const float* __restrict__ bo,
                                                     float* __restrict__ out) {
  __shared__ char sm[49152];
  int m0 = blockIdx.x * 64, n0 = blockIdx.y * 128;
  f4 acc[2][4];
  gemm_core_db(ctx, wo, m0, n0, sm, acc);
  int t = threadIdx.x, lane = t & 63, w = t >> 6, wr = w >> 1, wc = w & 1;
  #pragma unroll
  for (int mi = 0; mi < 2; ++mi)
    #pragma unroll
    for (int ni = 0; ni < 4; ++ni)
      #pragma unroll
      for (int r = 0; r < 4; ++r) {
        int m = m0 + wr * 32 + mi * 16 + ((lane >> 4) << 2) + r;
        int n = n0 + wc * 64 + ni * 16 + (lane & 15);
        out[(size_t)m * D_DIM + n] = acc[mi][ni][r] + bo[n];
      }
}

// ===================== flash attention (kv-split-2, 8 waves) =====================
// R9 structure + conditional cross-half exchange. NOTE: the constant
// SQ_LDS_BANK_CONFLICT=4194304 is intrinsic ds_read_b128 overhead
// (1048576 reads x 4 cy; m134: b128 ~12cy vs 8 ideal), NOT a fixable conflict.
// Occupancy pinned: ~128 VGPR/wave -> 16 waves/CU; LDS 64 KB -> 2 blocks/CU.
#define NTG 16  // kv tiles per group: 1024 / 64

// Build PV B-fragment for one 16-k slot from C-layout f32 P regs base..base+7.
// v_permlane32_swap_b32: vdst.lanes[32:63] <-> vsrc.lanes[0:31]. swap(A0,B0):
//   lo lane: A0 = A0_own,     B0 = A0 from hi partner
//   hi lane: A0 = B0 from lo, B0 = B0_own
// -> fragment words [A0, A1, B0, B1] for both halves. (Producers are separate
// asm blocks; compiler scheduling provides the permlane hazard distance.)
#define MKFRAG(dst, st, base) do {                                   \
    unsigned int A0_ = pkbf((st)[(base)+0], (st)[(base)+1]);         \
    unsigned int A1_ = pkbf((st)[(base)+2], (st)[(base)+3]);         \
    unsigned int B0_ = pkbf((st)[(base)+4], (st)[(base)+5]);         \
    unsigned int B1_ = pkbf((st)[(base)+6], (st)[(base)+7]);         \
    asm("v_permlane32_swap_b32 %0, %1" : "+v"(A0_), "+v"(B0_));      \
    asm("v_permlane32_swap_b32 %0, %1" : "+v"(A1_), "+v"(B1_));      \
    u32x4 wv_; wv_.x = A0_; wv_.y = A1_; wv_.z = B0_; wv_.w = B1_;   \
    dst = __builtin_bit_cast(b8, wv_);                               \
  } while (0)

// One 64-kv tile. KO/VO are compile-time byte offsets of the K / V tiles.
#define TILE(KO, VO) do {                                                     \
    f16v t0 = Z16, t1 = Z16;                                                  \
    __builtin_amdgcn_s_setprio(1);                                            \
    _Pragma("unroll")                                                         \
    for (int ks = 0; ks < 4; ++ks) {                                          \
      b8 kf0 = *reinterpret_cast<const AS_LDS b8*>(sb + koff[ks] + (KO));     \
      b8 kf1 = *reinterpret_cast<const AS_LDS b8*>(sb + koff[ks] + (KO) + 4096); \
      t0 = mfma32(kf0, qf[ks], t0);                                           \
      t1 = mfma32(kf1, qf[ks], t1);                                           \
    }                                                                         \
    __builtin_amdgcn_s_setprio(0);                                            \
    float a0 = fmaxf(fmaxf(t0[0], t0[8]),  fmaxf(t1[0], t1[8]));              \
    float a1 = fmaxf(fmaxf(t0[1], t0[9]),  fmaxf(t1[1], t1[9]));              \
    float a2 = fmaxf(fmaxf(t0[2], t0[10]), fmaxf(t1[2], t1[10]));             \
    float a3 = fmaxf(fmaxf(t0[3], t0[11]), fmaxf(t1[3], t1[11]));             \
    float a4 = fmaxf(fmaxf(t0[4], t0[12]), fmaxf(t1[4], t1[12]));             \
    float a5 = fmaxf(fmaxf(t0[5], t0[13]), fmaxf(t1[5], t1[13]));             \
    float a6 = fmaxf(fmaxf(t0[6], t0[14]), fmaxf(t1[6], t1[14]));             \
    float a7 = fmaxf(fmaxf(t0[7], t0[15]), fmaxf(t1[7], t1[15]));             \
    float mx = fmaxf(fmaxf(fmaxf(a0, a1), fmaxf(a2, a3)),                     \
                     fmaxf(fmaxf(a4, a5), fmaxf(a6, a7)));                    \
    if (!__all(mx - mr <= 11.5f)) {                                           \
      mx = xhalf_max(mx);              /* true global max (rare path) */      \
      float mn = fmaxf(mr, mx);                                               \
      float al = exp2v(mr - mn);                                              \
      mr = mn; lsum *= al; o0 *= al; o1 *= al;                                \
    }                                                                         \
    _Pragma("unroll")                                                         \
    for (int r = 0; r < 16; ++r) t0[r] = exp2v(t0[r] - mr);                   \
    _Pragma("unroll")                                                         \
    for (int r = 0; r < 16; ++r) t1[r] = exp2v(t1[r] - mr);                   \
    {                                                                         \
      float p0 = (t0[0] + t1[0]) + (t0[8]  + t1[8]);                          \
      float p1 = (t0[1] + t1[1]) + (t0[9]  + t1[9]);                          \
      float p2 = (t0[2] + t1[2]) + (t0[10] + t1[10]);                         \
      float p3 = (t0[3] + t1[3]) + (t0[11] + t1[11]);                         \
      float p4 = (t0[4] + t1[4]) + (t0[12] + t1[12]);                         \
      float p5 = (t0[5] + t1[5]) + (t0[13] + t1[13]);                         \
      float p6 = (t0[6] + t1[6]) + (t0[14] + t1[14]);                         \
      float p7 = (t0[7] + t1[7]) + (t0[15] + t1[15]);                         \
      lsum += ((p0 + p1) + (p2 + p3)) + ((p4 + p5) + (p6 + p7));              \
    }                                                                         \
    __builtin_amdgcn_s_setprio(1);                                            \
    _Pragma("unroll")                                                         \
    for (int ks = 0; ks < 4; ++ks) {                                          \
      b8 pa;                                                                  \
      if (ks == 0)      MKFRAG(pa, t0, 0);                                    \
      else if (ks == 1) MKFRAG(pa, t0, 8);                                    \
      else if (ks == 2) MKFRAG(pa, t1, 0);                                    \
      else              MKFRAG(pa, t1, 8);                                    \
      b8 vf0 = *reinterpret_cast<const AS_LDS b8*>(sb + koff[ks] + (VO));     \
      b8 vf1 = *reinterpret_cast<const AS_LDS b8*>(sb + koff[ks] + (VO) + 4096); \
      o0 = mfma32(vf0, pa, o0);                                               \
      o1 = mfma32(vf1, pa, o1);                                               \
    }                                                                         \
    __builtin_amdgcn_s_setprio(0);                                            \
  } while (0)

__global__ __launch_bounds__(512, 4) void attn_kernel(const __bf16* __restrict__ Q,
                                                      const __bf16* __restrict__ K,
                                                      const __bf16* __restrict__ Vt,
                                                      __bf16* __restrict__ ctx) {
  __shared__ char smem_[65536];
  int t = threadIdx.x, lane = t & 63, w = t >> 6;
  int lane31 = lane & 31, hi = lane >> 5;
  int grp = w >> 2, qs = w & 3, t256 = t & 255;

  // XCD swizzle: 512 blocks, 8 XCDs -> 64-block contiguous chunk per XCD
  // = 4 whole heads per XCD (16 q-tiles x same bh -> K/V L2-resident).
  int bid = blockIdx.x;
  int nid = (bid & 7) * 64 + (bid >> 3);
  int bh = nid >> 4, qtile = nid & 15;
  int b = bh >> 3, h = bh & 7;
  int q = qtile * 128 + qs * 32 + lane31;   // this lane's q row
  const __bf16* Qp = Q + (size_t)bh * S_LEN * HDIM;
  const __bf16* Kp = K + (size_t)bh * S_LEN * HDIM;
  const __bf16* Vp = Vt + (size_t)bh * HDIM * S_LEN;
  const int kv0 = grp * (S_LEN / 2);

  // Q fragments (B-operand: col=q=lane31, k=d=ks*16+hi*8+e). Q pre-scaled.
  b8 qf[4];
  #pragma unroll
  for (int ks = 0; ks < 4; ++ks)
    qf[ks] = *reinterpret_cast<const b8*>(&Qp[(size_t)q * HDIM + ks * 16 + hi * 8]);

  // 32-bit LDS base + per-ks fragment offsets (half1 = +4096 immediate since
  // (row+32)&7 == row&7). koff folds in grp*16384.
  const AS_LDS char* sb = (const AS_LDS char*)smem_;
  unsigned koff[4];
  #pragma unroll
  for (int ks = 0; ks < 4; ++ks) {
    int bc = hi * 16 + ks * 32;
    koff[ks] = grp * 16384 + lane31 * 128 + (bc ^ ((lane31 & 7) << 4));
  }

  // staging addresses (strength-reduced per iteration)
  int oA = t256 * 16, oB = 4096 + t256 * 16;
  int rA = oA >> 7, rB = oB >> 7;
  int sA = (oA & 127) ^ ((rA & 7) << 4), sB = (oB & 127) ^ ((rB & 7) << 4);
  const char* KgA = (const char*)Kp + (size_t)(kv0 + rA) * 128 + sA;   // += 8192/iter
  const char* KgB = (const char*)Kp + (size_t)(kv0 + rB) * 128 + sB;
  const char* VgA = (const char*)Vp + (size_t)rA * (S_LEN * 2) + (size_t)kv0 * 2 + sA;  // += 128/iter
  const char* VgB = (const char*)Vp + (size_t)rB * (S_LEN * 2) + (size_t)kv0 * 2 + sB;

  const f16v Z16 = {0,0,0,0,0,0,0,0,0,0,0,0,0,0,0,0};
  f16v o0 = Z16, o1 = Z16;   // O^T accum: rows d (0-31 / 32-63), col q
  float mr = -1e30f, lsum = 0.f;

  auto stage = [&](int buf) {
    char* ldsK = smem_ + grp * 16384 + buf * 8192;
    load_lds16(KgA, ldsK + oA);
    load_lds16(KgB, ldsK + oB);
    load_lds16(VgA, ldsK + 32768 + oA);
    load_lds16(VgB, ldsK + 32768 + oB);
    KgA += 8192; KgB += 8192; VgA += 128; VgB += 128;
  };

  stage(0);
  __syncthreads();

  #pragma unroll 1
  for (int it2 = 0; it2 < NTG / 2; ++it2) {
    stage(1);
    TILE(0, 32768);
    __syncthreads();
    if (it2 < NTG / 2 - 1) stage(0);
    TILE(8192, 40960);
    __syncthreads();
  }

  // ---- merge the two kv-halves (grp1 -> LDS -> grp0), then write ctx ----
  float l_own = xhalf_add(lsum);      // both halves' kv columns combined
  float* OL = (float*)smem_;          // [4 qs][64 d][32 q] f32 = 32 KiB (staging dead)
  float* ML = OL + 8192;              // m[4][32] then l[4][32]
  if (grp == 1) {
    #pragma unroll
    for (int g = 0; g < 4; ++g)
      #pragma unroll
      for (int j = 0; j < 4; ++j) {
        int d = 8 * g + 4 * hi + j;
        OL[(qs * 64 + d) * 32 + lane31]      = o0[4 * g + j];
        OL[(qs * 64 + 32 + d) * 32 + lane31] = o1[4 * g + j];
      }
    if (hi == 0) { ML[qs * 32 + lane31] = mr; ML[128 + qs * 32 + lane31] = l_own; }
  }
  __syncthreads();
  if (grp == 0) {
    float m1 = ML[qs * 32 + lane31], l1 = ML[128 + qs * 32 + lane31];
    float mm = fmaxf(mr, m1);
    float s0 = exp2v(mr - mm), s1 = exp2v(m1 - mm);
    float inv = 1.0f / (l_own * s0 + l1 * s1);
    __bf16* cp = ctx + (size_t)b * S_LEN * D_DIM + (size_t)q * D_DIM + (size_t)h * HDIM;
    #pragma unroll
    for (int g = 0; g < 4; ++g) {
      b4 v0, v1;
      #pragma unroll
      for (int j = 0; j < 4; ++j) {
        int d = 8 * g + 4 * hi + j;
        v0[j] = (__bf16)((o0[4 * g + j] * s0 + OL[(qs * 64 + d) * 32 + lane31] * s1) * inv);
        v1[j] = (__bf16)((o1[4 * g + j] * s0 + OL[(qs * 64 + 32 + d) * 32 + lane31] * s1) * inv);
      }
      int d0 = 8 * g + 4 * hi;
      *reinterpret_cast<b4*>(cp + d0)      = v0;
      *reinterpret_cast<b4*>(cp + 32 + d0) = v1;
    }
  }
}

// ===================== launch =====================
extern "C" void kernel_launch(void* const* d_in, const int* in_sizes, int n_in,
                              void* d_out, int out_size, void* d_ws, size_t ws_size,
                              hipStream_t stream) {
  const float* x  = (const float*)d_in[0];
  const float* Wq = (const float*)d_in[1];
  const float* bq = (const float*)d_in[2];
  const float* Wk = (const float*)d_in[3];
  const float* bk = (const float*)d_in[4];
  const float* Wv = (const float*)d_in[5];
  const float* bv = (const float*)d_in[6];
  const float* Wo = (const float*)d_in[7];
  const float* bo = (const float*)d_in[8];
  float* out = (float*)d_out;

  char* ws = (char*)d_ws;
  __bf16* xb   = (__bf16*)(ws);                               // 8192*512
  __bf16* wqb  = xb  + 4194304;                               // 512*512
  __bf16* wkb  = wqb + 262144;
  __bf16* wvb  = wkb + 262144;
  __bf16* wob  = wvb + 262144;
  __bf16* Qb   = wob + 262144;                                // 4*8*2048*64
  __bf16* Kb   = Qb  + 4194304;
  __bf16* Vtb  = Kb  + 4194304;                               // V transposed [B,H,HD,S]
  __bf16* ctxb = xb;  // reuse (x dead after QKV)

  cvt_kernel<<<dim3(4096), dim3(256), 0, stream>>>(x, xb);
  cvt_w_kernel<<<dim3(256, 4), dim3(256), 0, stream>>>(Wq, Wk, Wv, Wo, wqb, wkb, wvb, wob);
  gemm_qkv_kernel<<<dim3(128, 4, 3), dim3(256), 0, stream>>>(xb, wqb, wkb, wvb, bq, bk, bv, Qb, Kb, Vtb);
  attn_kernel<<<dim3(512), dim3(512), 0, stream>>>(Qb, Kb, Vtb, ctxb);
  gemm_o_kernel<<<dim3(128, 4), dim3(256), 0, stream>>>(ctxb, wob, bo, out);
}